// Round 6
// baseline (709.798 us; speedup 1.0000x reference)
//
#include <hip/hip_runtime.h>
#include <hip/hip_cooperative_groups.h>
#include <hip/hip_bf16.h>

namespace cg = cooperative_groups;

#define TPB 256
#define GRID 240

// =====================================================================
// shared helpers (256-thread block)
// =====================================================================
__device__ __forceinline__ int incl_scan256(int v, int* wsum){
  int tid = threadIdx.x, lane = tid & 63, w = tid >> 6;
  int ss = v;
  #pragma unroll
  for(int o = 1; o < 64; o <<= 1){ int t = __shfl_up(ss, o, 64); if(lane >= o) ss += t; }
  __syncthreads();
  if(lane == 63) wsum[w] = ss;
  __syncthreads();
  if(tid < 4){
    int t = wsum[tid];
    #pragma unroll
    for(int o = 1; o < 4; o <<= 1){ int uu = __shfl_up(t, o, 64); if(tid >= o) t += uu; }
    wsum[tid] = t;
  }
  __syncthreads();
  return ss + (w ? wsum[w-1] : 0);
}

__device__ __forceinline__ float block_sum_f(float v, float* fs){
  int tid = threadIdx.x, lane = tid & 63, w = tid >> 6;
  #pragma unroll
  for(int o = 32; o > 0; o >>= 1) v += __shfl_down(v, o, 64);
  __syncthreads();
  if(lane == 0) fs[w] = v;
  __syncthreads();
  return fs[0] + fs[1] + fs[2] + fs[3];
}

// exact top-k via 3-pass MSD radix-select on 32-bit mapped scores; tie-aware
// deterministic compaction (ties take lowest indices) — same SET as jax.lax.top_k
__device__ void pool256(const float* __restrict__ score, int n, int k,
                        int* __restrict__ perm, int* __restrict__ rank,
                        unsigned* keys, int* bins, int* wsum,
                        unsigned* s_pref, int* s_rk, int* s_found, int* s_cg){
  int tid = threadIdx.x;
  for(int i = tid; i < n; i += 256){
    unsigned uu = __float_as_uint(score[i]);
    uu ^= (uu & 0x80000000u) ? 0xFFFFFFFFu : 0x80000000u;
    keys[i] = uu;
  }
  if(tid == 0){ *s_pref = 0u; *s_rk = k; }
  __syncthreads();
  for(int pass = 0; pass < 3; ++pass){
    const int width = (pass < 2) ? 11 : 10;
    const int shift = (pass == 0) ? 21 : ((pass == 1) ? 10 : 0);
    const int nb = 1 << width;
    for(int b = tid; b < nb; b += 256) bins[b] = 0;
    __syncthreads();
    unsigned prefix = *s_pref; int rk = *s_rk;
    const int hs = shift + width;
    for(int i = tid; i < n; i += 256){
      unsigned kk = keys[i];
      bool match = (pass == 0) || ((kk >> hs) == (prefix >> hs));
      if(match) atomicAdd(&bins[(kk >> shift) & (nb-1)], 1);
    }
    __syncthreads();
    const int ipt = nb >> 8;        // 8 or 4
    int loc[8]; int s = 0;
    for(int q = 0; q < ipt; ++q){ int rr = tid*ipt + q; s += bins[nb-1-rr]; loc[q] = s; }
    int incl = incl_scan256(s, wsum);   // internal syncs separate reads from writes
    int excl = incl - s;
    for(int q = 0; q < ipt; ++q){ int rr = tid*ipt + q; bins[nb-1-rr] = excl + loc[q]; }
    __syncthreads();
    for(int b = tid; b < nb; b += 256){
      int cge = bins[b], cgt = (b+1 < nb) ? bins[b+1] : 0;
      if(cge >= rk && cgt < rk){ *s_found = b; *s_cg = cgt; }   // unique b
    }
    __syncthreads();
    if(tid == 0){ *s_pref |= ((unsigned)(*s_found)) << shift; *s_rk = rk - (*s_cg); }
    __syncthreads();
  }
  unsigned T = *s_pref; int r = *s_rk; int cgt_total = k - r;
  int CH = (n + 255) >> 8;
  int base = tid*CH, c_gt = 0, c_eq = 0;
  for(int q = 0; q < CH; ++q){
    int i = base + q;
    if(i < n){ unsigned uu = keys[i]; c_gt += (uu > T); c_eq += (uu == T); }
  }
  int packed = c_gt*8192 + c_eq;
  int incl2 = incl_scan256(packed, wsum);
  int excl2 = incl2 - packed;
  int gt_b = excl2 / 8192, eq_b = excl2 % 8192;
  for(int q = 0; q < CH; ++q){
    int i = base + q; if(i >= n) continue;
    unsigned uu = keys[i];
    if(uu > T){ int pos = gt_b++; perm[pos] = i; rank[i] = pos; }
    else if(uu == T){ int tr = eq_b++; if(tr < r){ int pos = cgt_total + tr; perm[pos] = i; rank[i] = pos; } }
  }
}

// =====================================================================
// cooperative mega kernel — the whole forward pass, 21 grid syncs
// =====================================================================
struct GP {
  const float* x; const int* ei;
  const float *W0,*b0,*W1,*b1,*W2,*b2,*W3,*b3;
  const float *p0,*p1,*p2;
  const float *Wu0,*bu0,*Wu1,*bu1,*Wu2,*bu2,*bng,*bnb;
  float* out;
  int n0, E, K1, K2, K3;
  int *cnt,*fillc,*cursor,*rowptr,*colidx;
  float *dinv0,*xa,*h0,*score;
  int *perm1,*rank1;
  float *hw1,*dinv1; int *rowbeg1,*rowend1,*col1; float *val1;
  float *h1; int *perm2,*rank2; float *hw2,*C2,*dinv2,*h2;
  int *perm3,*rank3; float *hw3,*C3,*dinv3,*h3;
  float *hu2,*hu1,*hw4,*bnp,*bnq;
};

union SMem {
  struct { unsigned keys[6144]; int bins[2048]; } pool;   // 32 KB
  float row[1216];
  float acc[256];
  float sh[8][32];
  float acc3[4][64];
};

__global__ __launch_bounds__(256)
void k_mega(GP p){
  cg::grid_group grid = cg::this_grid();
  __shared__ SMem u;
  __shared__ int wsum[16];
  __shared__ unsigned s_pref;
  __shared__ int s_rk, s_found, s_cg, s_base;
  __shared__ float fs[4];
  const int tid = threadIdx.x, bid = blockIdx.x;
  const int gsz = gridDim.x * blockDim.x, gtid = bid*blockDim.x + tid;
  const int n0 = p.n0, E = p.E, K1 = p.K1, K2 = p.K2, K3 = p.K3;

  // S0: zero counters
  for(int i = gtid; i < n0; i += gsz){ p.cnt[i] = 0; p.fillc[i] = 0; }
  if(gtid == 0) *p.cursor = 0;
  grid.sync();
  // S1: degree count (rows = dst = ei[1])
  for(int e = gtid; e < E; e += gsz) atomicAdd(&p.cnt[p.ei[E + e]], 1);
  grid.sync();
  // S2: rowptr scan (block 0)
  if(bid == 0){
    const int IPT = 24;                      // 256*24 = 6144 >= n0
    int base = tid*IPT, loc[IPT], s = 0;
    for(int q = 0; q < IPT; ++q){ int i = base + q; int v = (i < n0) ? p.cnt[i] : 0; s += v; loc[q] = s; }
    int incl = incl_scan256(s, wsum);
    int excl = incl - s;
    if(tid == 0) p.rowptr[0] = 0;
    for(int q = 0; q < IPT; ++q){ int i = base + q; if(i < n0) p.rowptr[i+1] = excl + loc[q]; }
  }
  grid.sync();
  // S3: CSR fill
  for(int e = gtid; e < E; e += gsz){
    int d = p.ei[E + e], s = p.ei[e];
    int pos = p.rowptr[d] + atomicAdd(&p.fillc[d], 1);
    p.colidx[pos] = s;
  }
  grid.sync();
  // S4: degree-normalized 3-channel aggregation + dinv0 + rank1 init
  //   xa[i] = 2*dinv0[i]*x[i] + sum_j A_ij * dinv0[j] * x[j]   (the dinv[None,:] factor!)
  for(int i = gtid; i < n0; i += gsz){
    float di = rsqrtf((float)p.cnt[i] + 2.0f);
    p.dinv0[i] = di;
    float s0 = 2.f*di*p.x[i*3], s1 = 2.f*di*p.x[i*3+1], s2 = 2.f*di*p.x[i*3+2];
    for(int q = p.rowptr[i]; q < p.rowptr[i+1]; ++q){
      int j = p.colidx[q];
      float dj = rsqrtf((float)p.cnt[j] + 2.0f);
      s0 += dj*p.x[j*3]; s1 += dj*p.x[j*3+1]; s2 += dj*p.x[j*3+2];
    }
    p.xa[i*3] = s0; p.xa[i*3+1] = s1; p.xa[i*3+2] = s2;
    p.rank1[i] = -1;
  }
  grid.sync();
  // S5: GCN0 = dinv0[i]*(xa·W0)+b0, relu, fused score(p0)
  for(int t = gtid; t < n0*32; t += gsz){
    int i = t >> 5, c = t & 31;
    float y = p.dinv0[i]*(p.xa[i*3]*p.W0[c] + p.xa[i*3+1]*p.W0[32+c] + p.xa[i*3+2]*p.W0[64+c]) + p.b0[c];
    y = fmaxf(y, 0.f); p.h0[t] = y;
    float pv = p.p0[c]; float sd = y*pv, nn = pv*pv;
    #pragma unroll
    for(int o = 16; o > 0; o >>= 1){ sd += __shfl_xor(sd, o, 32); nn += __shfl_xor(nn, o, 32); }
    if(c == 0) p.score[i] = tanhf(sd / sqrtf(nn));
  }
  grid.sync();
  // S6: pool1
  if(bid == 0) pool256(p.score, n0, K1, p.perm1, p.rank1, u.pool.keys, u.pool.bins, wsum, &s_pref, &s_rk, &s_found, &s_cg);
  grid.sync();
  // S7: mmp1 (raw, perm-gathered) || build B1 CSR + dinv1
  for(int t = gtid; t < K1*32; t += gsz){
    int i = t >> 5, c = t & 31; int idx = p.perm1[i]; float sc = p.score[idx];
    const float* hr = p.h0 + (size_t)idx*32;
    float s = 0.f;
    #pragma unroll
    for(int d = 0; d < 32; ++d) s += hr[d]*p.W1[d*32 + c];
    p.hw1[t] = sc*s;
  }
  for(int i = bid; i < K1; i += gridDim.x){
    for(int j = tid; j < K1; j += 256) u.row[j] = 0.f;
    __syncthreads();
    int d = p.perm1[i];
    int b = p.rowptr[d], len = p.rowptr[d+1] - b;
    for(int q = tid; q < len; q += 256){
      int s = p.colidx[b + q]; int rs = p.rank1[s];
      if(rs >= 0) atomicAdd(&u.row[rs], 2.0f);           // 2A (exact int adds)
    }
    for(int ww = tid; ww < len*8; ww += 256){
      int q = ww >> 3, sub = ww & 7;
      int s = p.colidx[b + q];
      for(int e2 = p.rowptr[s] + sub, ee = p.rowptr[s+1]; e2 < ee; e2 += 8){
        int r2 = p.rank1[p.colidx[e2]];
        if(r2 >= 0) atomicAdd(&u.row[r2], 1.0f);         // A^2 2-paths
      }
    }
    __syncthreads();
    if(tid == 0) u.row[i] = 0.f;                          // diag <- 0
    __syncthreads();
    float s = 0.f;
    for(int j = tid; j < K1; j += 256) s += u.row[j];
    float tot = block_sum_f(s, fs);
    if(tid == 0){ p.dinv1[i] = rsqrtf(tot + 2.0f); u.row[i] = 1.0f; }  // +I
    __syncthreads();
    const int CH = (1200 + 255) >> 8;  // 5
    int base = tid*CH, cnt2 = 0;
    for(int q = 0; q < CH; ++q){ int j = base + q; if(j < K1 && u.row[j] != 0.f) ++cnt2; }
    int incl = incl_scan256(cnt2, wsum);
    if(tid == 255) s_base = atomicAdd(p.cursor, incl);
    __syncthreads();
    int off = s_base + (incl - cnt2);
    for(int q = 0; q < CH; ++q){
      int j = base + q;
      if(j < K1 && u.row[j] != 0.f){ p.col1[off] = j; p.val1[off] = u.row[j]; ++off; }
    }
    if(tid == 0)   p.rowbeg1[i] = s_base;
    if(tid == 255) p.rowend1[i] = s_base + incl;
    __syncthreads();
  }
  grid.sync();
  // S8: GCN1 sparse (dinv applied at gather), relu, score(p1), rank2 init
  for(int i = gtid; i < K1; i += gsz) p.rank2[i] = -1;
  for(int t = gtid; t < K1*32; t += gsz){
    int i = t >> 5, c = t & 31;
    float acc = p.dinv1[i]*p.hw1[t];
    for(int q = p.rowbeg1[i]; q < p.rowend1[i]; ++q){
      int j = p.col1[q];
      acc += p.val1[q]*p.dinv1[j]*p.hw1[j*32 + c];
    }
    float y = p.dinv1[i]*acc + p.b1[c];
    y = fmaxf(y, 0.f); p.h1[t] = y;
    float pv = p.p1[c]; float sd = y*pv, nn = pv*pv;
    #pragma unroll
    for(int o = 16; o > 0; o >>= 1){ sd += __shfl_xor(sd, o, 32); nn += __shfl_xor(nn, o, 32); }
    if(c == 0) p.score[i] = tanhf(sd / sqrtf(nn));
  }
  grid.sync();
  // S9: pool2
  if(bid == 0) pool256(p.score, K1, K2, p.perm2, p.rank2, u.pool.keys, u.pool.bins, wsum, &s_pref, &s_rk, &s_found, &s_cg);
  grid.sync();
  // S10: mmp2 (raw) || two-hop level1 -> C2 + dinv2
  for(int t = gtid; t < K2*32; t += gsz){
    int i = t >> 5, c = t & 31; int idx = p.perm2[i]; float sc = p.score[idx];
    const float* hr = p.h1 + (size_t)idx*32;
    float s = 0.f;
    #pragma unroll
    for(int d = 0; d < 32; ++d) s += hr[d]*p.W2[d*32 + c];
    p.hw2[t] = sc*s;
  }
  for(int i = bid; i < K2; i += gridDim.x){
    for(int j = tid; j < K2; j += 256) u.acc[j] = 0.f;
    __syncthreads();
    int qi = p.perm2[i];
    int b = p.rowbeg1[qi], len = p.rowend1[qi] - b;
    for(int ww = tid; ww < len*8; ww += 256){
      int q = b + (ww >> 3), sub = ww & 7;
      int t2 = p.col1[q]; float v = p.val1[q];
      for(int e2 = p.rowbeg1[t2] + sub, ee = p.rowend1[t2]; e2 < ee; e2 += 8){
        int j = p.rank2[p.col1[e2]];
        if(j >= 0) atomicAdd(&u.acc[j], v*p.val1[e2]);   // exact int adds
      }
    }
    __syncthreads();
    if(tid == 0) u.acc[i] = 0.f;
    __syncthreads();
    float s = 0.f;
    for(int j = tid; j < K2; j += 256) s += u.acc[j];
    float tot = block_sum_f(s, fs);
    if(tid == 0) p.dinv2[i] = rsqrtf(tot + 2.0f);
    for(int j = tid; j < K2; j += 256) p.C2[(size_t)i*K2 + j] = u.acc[j];
    __syncthreads();
  }
  grid.sync();
  // S11: GCN2 dense (block/row), relu, score(p2), rank3 init
  for(int i = bid; i < K2; i += gridDim.x){
    int c = tid & 31, sg = tid >> 5;
    const float* Crow = p.C2 + (size_t)i*K2;
    float a = 0.f;
    for(int t2 = sg; t2 < K2; t2 += 8) a += Crow[t2]*p.dinv2[t2]*p.hw2[t2*32 + c];
    u.sh[sg][c] = a;
    __syncthreads();
    if(sg == 0){
      float aa = u.sh[0][c]+u.sh[1][c]+u.sh[2][c]+u.sh[3][c]+u.sh[4][c]+u.sh[5][c]+u.sh[6][c]+u.sh[7][c];
      aa += 2.f*p.dinv2[i]*p.hw2[i*32 + c];
      float y = p.dinv2[i]*aa + p.b2[c];
      y = fmaxf(y, 0.f);
      p.h2[i*32 + c] = y;
      float pv = p.p2[c]; float sd = y*pv, nn = pv*pv;
      #pragma unroll
      for(int o = 16; o > 0; o >>= 1){ sd += __shfl_xor(sd, o, 32); nn += __shfl_xor(nn, o, 32); }
      if(c == 0){ p.score[i] = tanhf(sd / sqrtf(nn)); p.rank3[i] = -1; }
    }
    __syncthreads();
  }
  grid.sync();
  // S12: pool3
  if(bid == 0) pool256(p.score, K2, K3, p.perm3, p.rank3, u.pool.keys, u.pool.bins, wsum, &s_pref, &s_rk, &s_found, &s_cg);
  grid.sync();
  // S13: mmp3 (raw) || two-hop level2 -> C3 + dinv3
  for(int t = gtid; t < K3*32; t += gsz){
    int i = t >> 5, c = t & 31; int idx = p.perm3[i]; float sc = p.score[idx];
    const float* hr = p.h2 + (size_t)idx*32;
    float s = 0.f;
    #pragma unroll
    for(int d = 0; d < 32; ++d) s += hr[d]*p.W3[d*32 + c];
    p.hw3[t] = sc*s;
  }
  if(bid < K3){
    int i = bid;
    int col = tid & 63, st = tid >> 6;
    int qi = p.perm3[i];
    int qj = (col < K3) ? p.perm3[col] : 0;
    float a = 0.f;
    if(col < K3){
      for(int t2 = st; t2 < K2; t2 += 4){
        float av = p.C2[(size_t)qi*K2 + t2] + ((t2 == qi) ? 1.f : 0.f);
        float bv = p.C2[(size_t)t2*K2 + qj] + ((t2 == qj) ? 1.f : 0.f);
        a += av*bv;
      }
    }
    u.acc3[st][col] = a;
    __syncthreads();
    if(st == 0){
      float v = u.acc3[0][col]+u.acc3[1][col]+u.acc3[2][col]+u.acc3[3][col];
      if(col == i) v = 0.f;
      if(col < K3) p.C3[(size_t)i*K3 + col] = v;
      float sv = (col < K3) ? v : 0.f;
      #pragma unroll
      for(int o = 32; o > 0; o >>= 1) sv += __shfl_down(sv, o, 64);
      if(col == 0) p.dinv3[i] = rsqrtf(sv + 2.0f);
    }
  }
  grid.sync();
  // S14: GCN3 dense -> h3
  for(int i = bid; i < K3; i += gridDim.x){
    int c = tid & 31, sg = tid >> 5;
    const float* Crow = p.C3 + (size_t)i*K3;
    float a = 0.f;
    for(int t2 = sg; t2 < K3; t2 += 8) a += Crow[t2]*p.dinv3[t2]*p.hw3[t2*32 + c];
    u.sh[sg][c] = a;
    __syncthreads();
    if(sg == 0){
      float aa = u.sh[0][c]+u.sh[1][c]+u.sh[2][c]+u.sh[3][c]+u.sh[4][c]+u.sh[5][c]+u.sh[6][c]+u.sh[7][c];
      aa += 2.f*p.dinv3[i]*p.hw3[i*32 + c];
      float y = p.dinv3[i]*aa + p.b3[c];
      p.h3[i*32 + c] = fmaxf(y, 0.f);
    }
    __syncthreads();
  }
  grid.sync();
  // S15: up0 add+mm (raw) -> hw2 (reuse)
  for(int t = gtid; t < K2*32; t += gsz){
    int i = t >> 5, c = t & 31; int r = p.rank3[i];
    float s = 0.f;
    #pragma unroll
    for(int d = 0; d < 32; ++d){
      float z = p.h2[i*32 + d] + ((r >= 0) ? p.h3[r*32 + d] : 0.f);
      s += z*p.Wu0[d*32 + c];
    }
    p.hw2[t] = s;
  }
  grid.sync();
  // S16: up0 dense GCN -> hu2 (relu)
  for(int i = bid; i < K2; i += gridDim.x){
    int c = tid & 31, sg = tid >> 5;
    const float* Crow = p.C2 + (size_t)i*K2;
    float a = 0.f;
    for(int t2 = sg; t2 < K2; t2 += 8) a += Crow[t2]*p.dinv2[t2]*p.hw2[t2*32 + c];
    u.sh[sg][c] = a;
    __syncthreads();
    if(sg == 0){
      float aa = u.sh[0][c]+u.sh[1][c]+u.sh[2][c]+u.sh[3][c]+u.sh[4][c]+u.sh[5][c]+u.sh[6][c]+u.sh[7][c];
      aa += 2.f*p.dinv2[i]*p.hw2[i*32 + c];
      float y = p.dinv2[i]*aa + p.bu0[c];
      p.hu2[i*32 + c] = fmaxf(y, 0.f);
    }
    __syncthreads();
  }
  grid.sync();
  // S17: up1 add+mm (raw) -> hw1 (reuse)
  for(int t = gtid; t < K1*32; t += gsz){
    int i = t >> 5, c = t & 31; int r = p.rank2[i];
    float s = 0.f;
    #pragma unroll
    for(int d = 0; d < 32; ++d){
      float z = p.h1[i*32 + d] + ((r >= 0) ? p.hu2[r*32 + d] : 0.f);
      s += z*p.Wu1[d*32 + c];
    }
    p.hw1[t] = s;
  }
  grid.sync();
  // S18: up1 sparse GCN -> hu1 (relu)
  for(int t = gtid; t < K1*32; t += gsz){
    int i = t >> 5, c = t & 31;
    float acc = p.dinv1[i]*p.hw1[t];
    for(int q = p.rowbeg1[i]; q < p.rowend1[i]; ++q){
      int j = p.col1[q];
      acc += p.val1[q]*p.dinv1[j]*p.hw1[j*32 + c];
    }
    float y = p.dinv1[i]*acc + p.bu1[c];
    p.hu1[t] = fmaxf(y, 0.f);
  }
  grid.sync();
  // S19: up2 add+mm (dinv0 folded) -> hw4 (n0 x 4)
  for(int t = gtid; t < n0*4; t += gsz){
    int i = t >> 2, c = t & 3; int r = p.rank1[i];
    float s = 0.f;
    #pragma unroll
    for(int d = 0; d < 32; ++d){
      float z = p.h0[i*32 + d] + ((r >= 0) ? p.hu1[r*32 + d] : 0.f);
      s += z*p.Wu2[d*4 + c];
    }
    p.hw4[t] = p.dinv0[i]*s;
  }
  grid.sync();
  // S20: final CSR GCN (no relu) -> out, fused BN partial sums
  {
    float vs = 0.f, vq = 0.f;
    for(int t = gtid; t < n0*4; t += gsz){
      int i = t >> 2, c = t & 3;
      float acc = 2.f*p.hw4[t];
      for(int q = p.rowptr[i]; q < p.rowptr[i+1]; ++q) acc += p.hw4[p.colidx[q]*4 + c];
      float y = p.dinv0[i]*acc + p.bu2[c];
      p.out[t] = y;
      if(c == 0){ vs += y; vq += y*y; }
    }
    float bs = block_sum_f(vs, fs);
    float bq = block_sum_f(vq, fs);
    if(tid == 0){ p.bnp[bid] = bs; p.bnq[bid] = bq; }
  }
  grid.sync();
  // S21: BN + sigmoid on column 0 (each block redundantly reduces partials)
  {
    float sv = (tid < (int)gridDim.x) ? p.bnp[tid] : 0.f;
    float qv = (tid < (int)gridDim.x) ? p.bnq[tid] : 0.f;
    float tsum = block_sum_f(sv, fs);
    float tsq  = block_sum_f(qv, fs);
    float mean = tsum / n0;
    float var  = tsq / n0 - mean*mean;
    float scale = p.bng[0]*rsqrtf(var + 1e-5f);
    float beta  = p.bnb[0];
    for(int i = gtid; i < n0; i += gsz){
      float r = scale*(p.out[i*4] - mean) + beta;
      p.out[i*4] = 1.f/(1.f + expf(-r));
    }
  }
}

// =====================================================================
// FALLBACK PATH — proven R4 kernels (used only if cooperative launch fails)
// =====================================================================
__global__ void k_count(const int* __restrict__ ei, int E, int* __restrict__ cnt){
  int e = blockIdx.x*blockDim.x + threadIdx.x;
  if(e < E) atomicAdd(&cnt[ei[E + e]], 1);
}

template<int IPT>
__global__ void k_scan(const int* __restrict__ cnt, int n, int* __restrict__ rowptr){
  int tid = threadIdx.x;
  int base = tid * IPT;
  int loc[IPT]; int s = 0;
  #pragma unroll
  for(int q = 0; q < IPT; ++q){ int i = base + q; int v = (i < n) ? cnt[i] : 0; s += v; loc[q] = s; }
  int lane = tid & 63, w = tid >> 6;
  int ss = s;
  #pragma unroll
  for(int o = 1; o < 64; o <<= 1){ int t = __shfl_up(ss, o, 64); if(lane >= o) ss += t; }
  __shared__ int wsum[16];
  if(lane == 63) wsum[w] = ss;
  __syncthreads();
  if(tid < 16){
    int t = wsum[tid];
    for(int o = 1; o < 16; o <<= 1){ int uu = __shfl_up(t, o, 64); if(tid >= o) t += uu; }
    wsum[tid] = t;
  }
  __syncthreads();
  int excl = ss - s + (w > 0 ? wsum[w-1] : 0);
  if(tid == 0) rowptr[0] = 0;
  #pragma unroll
  for(int q = 0; q < IPT; ++q){ int i = base + q; if(i < n) rowptr[i+1] = excl + loc[q]; }
}

__global__ void k_fill(const int* __restrict__ ei, int E, const int* __restrict__ rowptr,
                       int* __restrict__ fill, int* __restrict__ colidx){
  int e = blockIdx.x*blockDim.x + threadIdx.x;
  if(e >= E) return;
  int d = ei[E + e], s = ei[e];
  int p = rowptr[d] + atomicAdd(&fill[d], 1);
  colidx[p] = s;
}

__global__ void k_mm_dinv(const float* __restrict__ h, const float* __restrict__ W,
                          const float* __restrict__ dinv, const int* __restrict__ cnt,
                          float* __restrict__ dinv_out, float* __restrict__ out,
                          int n, int cin, int cout){
  int t = blockIdx.x*blockDim.x + threadIdx.x;
  if(t >= n*cout) return;
  int i = t / cout, c = t - i*cout;
  float dv;
  if(cnt){ dv = rsqrtf((float)cnt[i] + 2.0f); if(c == 0) dinv_out[i] = dv; }
  else dv = dinv[i];
  float s = 0.f;
  for(int d = 0; d < cin; ++d) s += h[i*cin + d] * W[d*cout + c];
  out[t] = dv * s;
}

template<int COUT>
__global__ void k_addup_mm(const float* __restrict__ base, const float* __restrict__ h,
                           const int* __restrict__ rank, const float* __restrict__ W,
                           const float* __restrict__ dinv, float* __restrict__ out, int n){
  int t = blockIdx.x*blockDim.x + threadIdx.x;
  if(t >= n*COUT) return;
  int i = t / COUT, c = t - i*COUT;
  int r = rank[i];
  const float* br = base + (size_t)i*32;
  const float* hr = h + (size_t)(r >= 0 ? r : 0)*32;
  float s = 0.f;
  #pragma unroll
  for(int d = 0; d < 32; ++d){
    float z = br[d] + ((r >= 0) ? hr[d] : 0.f);
    s += z * W[d*COUT + c];
  }
  out[t] = dinv[i] * s;
}

template<int C, bool RELU, bool SCORE>
__global__ void k_csr_gcn(const int* __restrict__ rowptr, const int* __restrict__ colidx,
                          const float* __restrict__ xwd, const float* __restrict__ dinv,
                          const float* __restrict__ bias, float* __restrict__ out, int n,
                          const float* __restrict__ pvec, float* __restrict__ score){
  int t = blockIdx.x*blockDim.x + threadIdx.x;
  if(t >= n*C) return;
  int i = t / C, c = t % C;
  float acc = 2.0f * xwd[i*C + c];
  int b = rowptr[i], e = rowptr[i+1];
  for(int p = b; p < e; ++p) acc += xwd[colidx[p]*C + c];
  float y = dinv[i]*acc + bias[c];
  y = RELU ? fmaxf(y, 0.f) : y;
  out[t] = y;
  if(SCORE){
    float pv = pvec[c];
    float sd = y*pv, nn = pv*pv;
    #pragma unroll
    for(int o = 16; o > 0; o >>= 1){ sd += __shfl_xor(sd, o, 32); nn += __shfl_xor(nn, o, 32); }
    if(c == 0) score[i] = tanhf(sd / sqrtf(nn));
  }
}

template<int NMAX>
__global__ __launch_bounds__(1024)
void k_pool_radix(const float* __restrict__ score, const float* __restrict__ h,
                  int n, int k, int* __restrict__ perm, int* __restrict__ rank,
                  float* __restrict__ hout){
  __shared__ unsigned keys[NMAX];
  __shared__ int bins[2048];
  __shared__ int wsum[16];
  __shared__ unsigned s_prefix;
  __shared__ int s_rk, s_found, s_cntgt;
  int tid = threadIdx.x, lane = tid & 63, w = tid >> 6;
  for(int i = tid; i < n; i += 1024){
    rank[i] = -1;
    unsigned uu = __float_as_uint(score[i]);
    uu ^= (uu & 0x80000000u) ? 0xFFFFFFFFu : 0x80000000u;
    keys[i] = uu;
  }
  if(tid == 0){ s_prefix = 0u; s_rk = k; }
  __syncthreads();
  for(int pass = 0; pass < 3; ++pass){
    const int width = (pass < 2) ? 11 : 10;
    const int shift = (pass == 0) ? 21 : ((pass == 1) ? 10 : 0);
    const int nb = 1 << width;
    for(int b2 = tid; b2 < nb; b2 += 1024) bins[b2] = 0;
    __syncthreads();
    unsigned prefix = s_prefix;
    int rk = s_rk;
    const int hs = shift + width;
    for(int i = tid; i < n; i += 1024){
      unsigned kk = keys[i];
      bool match = (pass == 0) || ((kk >> hs) == (prefix >> hs));
      if(match) atomicAdd(&bins[(kk >> shift) & (nb-1)], 1);
    }
    __syncthreads();
    int ipt = (nb + 1023) >> 10;
    int loc0 = 0, loc1 = 0, s = 0;
    { int r = tid*ipt; int v = (r < nb) ? bins[nb-1-r] : 0; s += v; loc0 = s;
      if(ipt == 2){ int r2 = r+1; int v2 = (r2 < nb) ? bins[nb-1-r2] : 0; s += v2; loc1 = s; } }
    int ss = s;
    #pragma unroll
    for(int o = 1; o < 64; o <<= 1){ int t2 = __shfl_up(ss, o, 64); if(lane >= o) ss += t2; }
    if(lane == 63) wsum[w] = ss;
    __syncthreads();
    if(tid < 16){
      int t2 = wsum[tid];
      #pragma unroll
      for(int o = 1; o < 16; o <<= 1){ int u2 = __shfl_up(t2, o, 64); if(tid >= o) t2 += u2; }
      wsum[tid] = t2;
    }
    __syncthreads();
    int excl = ss - s + (w ? wsum[w-1] : 0);
    { int r = tid*ipt; if(r < nb) bins[nb-1-r] = excl + loc0;
      if(ipt == 2){ int r2 = r+1; if(r2 < nb) bins[nb-1-r2] = excl + loc1; } }
    __syncthreads();
    for(int b2 = tid; b2 < nb; b2 += 1024){
      int cge = bins[b2];
      int cgt = (b2+1 < nb) ? bins[b2+1] : 0;
      if(cge >= rk && cgt < rk){ s_found = b2; s_cntgt = cgt; }
    }
    __syncthreads();
    if(tid == 0){ s_prefix |= ((unsigned)s_found) << shift; s_rk -= s_cntgt; }
    __syncthreads();
  }
  unsigned T = s_prefix;
  int r = s_rk;
  int cgt_total = k - r;
  int CH = (n + 1023) >> 10;
  int base = tid*CH, c_gt = 0, c_eq = 0;
  for(int q = 0; q < CH; ++q){
    int i = base+q;
    if(i < n){ unsigned uu = keys[i]; c_gt += (uu > T); c_eq += (uu == T); }
  }
  int packed = c_gt*8192 + c_eq;
  int ss2 = packed;
  #pragma unroll
  for(int o = 1; o < 64; o <<= 1){ int t2 = __shfl_up(ss2, o, 64); if(lane >= o) ss2 += t2; }
  if(lane == 63) wsum[w] = ss2;
  __syncthreads();
  if(tid < 16){
    int t2 = wsum[tid];
    #pragma unroll
    for(int o = 1; o < 16; o <<= 1){ int u2 = __shfl_up(t2, o, 64); if(tid >= o) t2 += u2; }
    wsum[tid] = t2;
  }
  __syncthreads();
  int excl2 = ss2 - packed + (w ? wsum[w-1] : 0);
  int gt_before = excl2 / 8192, eq_before = excl2 % 8192;
  for(int q = 0; q < CH; ++q){
    int i = base+q;
    if(i >= n) continue;
    unsigned uu = keys[i];
    if(uu > T){ int pos = gt_before++; perm[pos] = i; rank[i] = pos; }
    else if(uu == T){
      int tr = eq_before++;
      if(tr < r){ int pos = cgt_total + tr; perm[pos] = i; rank[i] = pos; }
    }
  }
  __syncthreads();
  for(int t = tid; t < k*32; t += 1024){
    int i = t >> 5, c = t & 31;
    int idx = perm[i];
    hout[t] = h[(size_t)idx*32 + c] * score[idx];
  }
}

__global__ __launch_bounds__(256)
void k_build_B1(const int* __restrict__ rowptr, const int* __restrict__ colidx,
                const int* __restrict__ perm1, const int* __restrict__ rank1, int K1,
                float* __restrict__ dinv1, int* __restrict__ rowbeg, int* __restrict__ rowend,
                int* __restrict__ col1, float* __restrict__ val1, int* __restrict__ cursor){
  __shared__ float row[1216];
  __shared__ int wsum[4];
  __shared__ float fs[4];
  __shared__ int s_base;
  int tid = threadIdx.x, lane = tid & 63, w = tid >> 6;
  int i = blockIdx.x;
  for(int j = tid; j < K1; j += 256) row[j] = 0.f;
  __syncthreads();
  int d = perm1[i];
  int b = rowptr[d], len = rowptr[d+1]-b;
  for(int p = tid; p < len; p += 256){
    int s = colidx[b+p]; int rs = rank1[s];
    if(rs >= 0) atomicAdd(&row[rs], 2.0f);
  }
  for(int ww = tid; ww < len*8; ww += 256){
    int p = ww >> 3, sub = ww & 7;
    int s = colidx[b+p];
    for(int q = rowptr[s]+sub, qe = rowptr[s+1]; q < qe; q += 8){
      int r2 = rank1[colidx[q]];
      if(r2 >= 0) atomicAdd(&row[r2], 1.0f);
    }
  }
  __syncthreads();
  if(tid == 0) row[i] = 0.f;
  __syncthreads();
  float s = 0.f;
  for(int j = tid; j < K1; j += 256) s += row[j];
  for(int o = 32; o > 0; o >>= 1) s += __shfl_down(s, o, 64);
  if(lane == 0) fs[w] = s;
  __syncthreads();
  if(tid == 0){
    dinv1[i] = rsqrtf(fs[0]+fs[1]+fs[2]+fs[3] + 2.0f);
    row[i] = 1.0f;
  }
  __syncthreads();
  int CH = (K1 + 255) >> 8;
  int base = tid*CH, cnt = 0;
  for(int q = 0; q < CH; ++q){ int j = base+q; if(j < K1 && row[j] != 0.f) ++cnt; }
  int ss = cnt;
  #pragma unroll
  for(int o = 1; o < 64; o <<= 1){ int t2 = __shfl_up(ss, o, 64); if(lane >= o) ss += t2; }
  if(lane == 63) wsum[w] = ss;
  __syncthreads();
  if(tid < 4){
    int t2 = wsum[tid];
    for(int o = 1; o < 4; o <<= 1){ int u2 = __shfl_up(t2, o, 64); if(tid >= o) t2 += u2; }
    wsum[tid] = t2;
  }
  __syncthreads();
  if(tid == 0) s_base = atomicAdd(cursor, wsum[3]);
  __syncthreads();
  int off = s_base + ss - cnt + (w ? wsum[w-1] : 0);
  for(int q = 0; q < CH; ++q){
    int j = base+q;
    if(j < K1 && row[j] != 0.f){ col1[off] = j; val1[off] = row[j]; ++off; }
  }
  if(tid == 0){ rowbeg[i] = s_base; rowend[i] = s_base + wsum[3]; }
}

template<bool RELU, bool SCORE>
__global__ void k_spmm_gcn(const int* __restrict__ rb, const int* __restrict__ re,
                           const int* __restrict__ ci, const float* __restrict__ cv,
                           const float* __restrict__ hwd, const float* __restrict__ dinv,
                           const float* __restrict__ bias, float* __restrict__ out, int n,
                           const float* __restrict__ pvec, float* __restrict__ score){
  int t = blockIdx.x*blockDim.x + threadIdx.x;
  if(t >= n*32) return;
  int i = t >> 5, c = t & 31;
  float acc = hwd[i*32 + c];
  for(int p = rb[i], e = re[i]; p < e; ++p) acc += cv[p]*hwd[ci[p]*32 + c];
  float y = dinv[i]*acc + bias[c];
  y = RELU ? fmaxf(y, 0.f) : y;
  out[t] = y;
  if(SCORE){
    float pv = pvec[c];
    float sd = y*pv, nn = pv*pv;
    #pragma unroll
    for(int o = 16; o > 0; o >>= 1){ sd += __shfl_xor(sd, o, 32); nn += __shfl_xor(nn, o, 32); }
    if(c == 0) score[i] = tanhf(sd / sqrtf(nn));
  }
}

__global__ __launch_bounds__(256)
void k_twohop_sp(const int* __restrict__ rb, const int* __restrict__ re,
                 const int* __restrict__ ci, const float* __restrict__ cv,
                 const int* __restrict__ perm2, const int* __restrict__ rank2,
                 float* __restrict__ C2, float* __restrict__ dinv2, int K2){
  __shared__ float acc[256];
  __shared__ float fs[4];
  int i = blockIdx.x, tid = threadIdx.x, lane = tid & 63, w = tid >> 6;
  for(int j = tid; j < K2; j += 256) acc[j] = 0.f;
  __syncthreads();
  int qi = perm2[i];
  int b = rb[qi], len = re[qi]-b;
  for(int ww = tid; ww < len*8; ww += 256){
    int p = b + (ww >> 3), sub = ww & 7;
    int t = ci[p]; float v = cv[p];
    for(int q = rb[t] + sub, qe = re[t]; q < qe; q += 8){
      int j = rank2[ci[q]];
      if(j >= 0) atomicAdd(&acc[j], v*cv[q]);
    }
  }
  __syncthreads();
  if(tid == 0) acc[i] = 0.f;
  __syncthreads();
  float s = 0.f;
  for(int j = tid; j < K2; j += 256) s += acc[j];
  for(int o = 32; o > 0; o >>= 1) s += __shfl_down(s, o, 64);
  if(lane == 0) fs[w] = s;
  __syncthreads();
  if(tid == 0) dinv2[i] = rsqrtf(fs[0]+fs[1]+fs[2]+fs[3] + 2.0f);
  for(int j = tid; j < K2; j += 256) C2[(size_t)i*K2 + j] = acc[j];
}

template<bool RELU, bool SCORE>
__global__ void k_dgcn_row(const float* __restrict__ C, const float* __restrict__ hwd,
                           const float* __restrict__ dinv, const float* __restrict__ bias,
                           float* __restrict__ out, int n,
                           const float* __restrict__ pvec, float* __restrict__ score){
  __shared__ float sh[8][32];
  int i = blockIdx.x;
  int c = threadIdx.x & 31, s = threadIdx.x >> 5;
  const float* row = C + (size_t)i*n;
  float acc = 0.f;
  for(int t = s; t < n; t += 8) acc += row[t]*hwd[t*32 + c];
  sh[s][c] = acc;
  __syncthreads();
  if(s == 0){
    float a = sh[0][c]+sh[1][c]+sh[2][c]+sh[3][c]+sh[4][c]+sh[5][c]+sh[6][c]+sh[7][c];
    a += 2.f*hwd[i*32 + c];
    float y = dinv[i]*a + bias[c];
    y = RELU ? fmaxf(y, 0.f) : y;
    out[i*32 + c] = y;
    if(SCORE){
      float pv = pvec[c];
      float sd = y*pv, nn = pv*pv;
      #pragma unroll
      for(int o = 16; o > 0; o >>= 1){ sd += __shfl_xor(sd, o, 32); nn += __shfl_xor(nn, o, 32); }
      if(c == 0) score[i] = tanhf(sd / sqrtf(nn));
    }
  }
}

__global__ __launch_bounds__(256)
void k_twohop_d3(const float* __restrict__ C2, int n, const int* __restrict__ perm3,
                 int k, float* __restrict__ C3, float* __restrict__ dinv3){
  __shared__ float acc[4][64];
  int i = blockIdx.x, tid = threadIdx.x;
  int col = tid & 63, st = tid >> 6;
  int qi = perm3[i];
  int qj = (col < k) ? perm3[col] : 0;
  float a = 0.f;
  if(col < k){
    for(int tt = st; tt < n; tt += 4){
      float av = C2[(size_t)qi*n + tt] + ((tt == qi) ? 1.f : 0.f);
      float bv = C2[(size_t)tt*n + qj] + ((tt == qj) ? 1.f : 0.f);
      a += av * bv;
    }
  }
  acc[st][col] = a;
  __syncthreads();
  if(st == 0){
    float v = acc[0][col]+acc[1][col]+acc[2][col]+acc[3][col];
    if(col == i) v = 0.f;
    if(col < k) C3[(size_t)i*k + col] = v;
    float sv = (col < k) ? v : 0.f;
    #pragma unroll
    for(int o = 32; o > 0; o >>= 1) sv += __shfl_down(sv, o, 64);
    if(col == 0) dinv3[i] = rsqrtf(sv + 2.0f);
  }
}

__global__ void k_bn(float* __restrict__ out, int n, const float* __restrict__ g,
                     const float* __restrict__ b){
  __shared__ float sh[16];
  __shared__ float sval;
  int tid = threadIdx.x, lane = tid & 63, w = tid >> 6;
  int nw = blockDim.x >> 6;
  float s = 0.f;
  for(int i = tid; i < n; i += blockDim.x) s += out[i*4];
  for(int o = 32; o > 0; o >>= 1) s += __shfl_down(s, o, 64);
  if(lane == 0) sh[w] = s;
  __syncthreads();
  if(tid == 0){ float t = 0.f; for(int q = 0; q < nw; ++q) t += sh[q]; sval = t / n; }
  __syncthreads();
  float mean = sval;
  float v = 0.f;
  for(int i = tid; i < n; i += blockDim.x){ float d = out[i*4] - mean; v += d*d; }
  for(int o = 32; o > 0; o >>= 1) v += __shfl_down(v, o, 64);
  __syncthreads();
  if(lane == 0) sh[w] = v;
  __syncthreads();
  if(tid == 0){ float t = 0.f; for(int q = 0; q < nw; ++q) t += sh[q]; sval = t / n; }
  __syncthreads();
  float var = sval;
  float scale = g[0] * rsqrtf(var + 1e-5f);
  float beta = b[0];
  for(int i = tid; i < n; i += blockDim.x){
    float r = scale*(out[i*4] - mean) + beta;
    out[i*4] = 1.f / (1.f + expf(-r));
  }
}

// =====================================================================
extern "C" void kernel_launch(void* const* d_in, const int* in_sizes, int n_in,
                              void* d_out, int out_size, void* d_ws, size_t ws_size,
                              hipStream_t stream){
  const float* x  =(const float*)d_in[0];
  const int*   ei =(const int*)  d_in[1];
  const float* W0 =(const float*)d_in[2];  const float* b0 =(const float*)d_in[3];
  const float* W1 =(const float*)d_in[4];  const float* b1 =(const float*)d_in[5];
  const float* W2 =(const float*)d_in[6];  const float* b2 =(const float*)d_in[7];
  const float* W3 =(const float*)d_in[8];  const float* b3 =(const float*)d_in[9];
  const float* p0 =(const float*)d_in[10];
  const float* p1 =(const float*)d_in[11];
  const float* p2 =(const float*)d_in[12];
  const float* Wu0=(const float*)d_in[13]; const float* bu0=(const float*)d_in[14];
  const float* Wu1=(const float*)d_in[15]; const float* bu1=(const float*)d_in[16];
  const float* Wu2=(const float*)d_in[17]; const float* bu2=(const float*)d_in[18];
  const float* bng=(const float*)d_in[19]; const float* bnb=(const float*)d_in[20];
  float* out = (float*)d_out;

  const int n0 = in_sizes[0] / 3;       // 6000
  const int E  = in_sizes[1] / 2;       // 96000
  const int K1 = (n0 + 4) / 5;          // 1200
  const int K2 = (K1 + 4) / 5;          // 240
  const int K3 = (K2 + 4) / 5;          // 48
  const int CAP1 = 512*1024;

  char* wsp = (char*)d_ws; size_t off = 0;
  auto alloc = [&](size_t bytes)->char*{
    char* p = wsp + off; off = (off + bytes + 255) & ~((size_t)255); return p;
  };

  int*   zreg   = (int*)  alloc((size_t)(2*n0+64)*4);
  int*   cnt    = zreg;
  int*   fillc  = zreg + n0;
  int*   cursor = zreg + 2*n0;
  int*   rowptr = (int*)  alloc((size_t)(n0+1)*4);
  int*   colidx = (int*)  alloc((size_t)E*4);
  float* dinv0  = (float*)alloc((size_t)n0*4);
  float* hwd    = (float*)alloc((size_t)n0*32*4);   // fallback temps
  float* xa     = (float*)alloc((size_t)n0*3*4);
  float* h0     = (float*)alloc((size_t)n0*32*4);
  float* score  = (float*)alloc((size_t)n0*4);
  int*   perm1  = (int*)  alloc((size_t)K1*4);
  int*   rank1  = (int*)  alloc((size_t)n0*4);
  float* h1p    = (float*)alloc((size_t)K1*32*4);   // fallback
  float* hw1    = (float*)alloc((size_t)K1*32*4);
  float* dinv1  = (float*)alloc((size_t)K1*4);
  int*   rowbeg1= (int*)  alloc((size_t)K1*4);
  int*   rowend1= (int*)  alloc((size_t)K1*4);
  int*   col1   = (int*)  alloc((size_t)CAP1*4);
  float* val1   = (float*)alloc((size_t)CAP1*4);
  float* h1     = (float*)alloc((size_t)K1*32*4);
  int*   perm2  = (int*)  alloc((size_t)K2*4);
  int*   rank2  = (int*)  alloc((size_t)K1*4);
  float* h2p    = (float*)alloc((size_t)K2*32*4);   // fallback
  float* hw2    = (float*)alloc((size_t)K2*32*4);
  float* C2     = (float*)alloc((size_t)K2*K2*4);
  float* dinv2  = (float*)alloc((size_t)K2*4);
  float* h2     = (float*)alloc((size_t)K2*32*4);
  int*   perm3  = (int*)  alloc((size_t)K3*4);
  int*   rank3  = (int*)  alloc((size_t)K2*4);
  float* h3p    = (float*)alloc((size_t)K3*32*4);   // fallback
  float* hw3    = (float*)alloc((size_t)K3*32*4);
  float* C3     = (float*)alloc((size_t)K3*K3*4);
  float* dinv3  = (float*)alloc((size_t)K3*4);
  float* h3     = (float*)alloc((size_t)K3*32*4);
  float* hu2    = (float*)alloc((size_t)K2*32*4);
  float* hu1    = (float*)alloc((size_t)K1*32*4);
  float* hw4    = (float*)alloc((size_t)n0*4*4);
  float* bnp    = (float*)alloc((size_t)256*4);
  float* bnq    = (float*)alloc((size_t)256*4);

  // ---------------- cooperative single-kernel path ----------------
  GP gp;
  gp.x=x; gp.ei=ei;
  gp.W0=W0; gp.b0=b0; gp.W1=W1; gp.b1=b1; gp.W2=W2; gp.b2=b2; gp.W3=W3; gp.b3=b3;
  gp.p0=p0; gp.p1=p1; gp.p2=p2;
  gp.Wu0=Wu0; gp.bu0=bu0; gp.Wu1=Wu1; gp.bu1=bu1; gp.Wu2=Wu2; gp.bu2=bu2;
  gp.bng=bng; gp.bnb=bnb;
  gp.out=out;
  gp.n0=n0; gp.E=E; gp.K1=K1; gp.K2=K2; gp.K3=K3;
  gp.cnt=cnt; gp.fillc=fillc; gp.cursor=cursor; gp.rowptr=rowptr; gp.colidx=colidx;
  gp.dinv0=dinv0; gp.xa=xa; gp.h0=h0; gp.score=score;
  gp.perm1=perm1; gp.rank1=rank1;
  gp.hw1=hw1; gp.dinv1=dinv1; gp.rowbeg1=rowbeg1; gp.rowend1=rowend1; gp.col1=col1; gp.val1=val1;
  gp.h1=h1; gp.perm2=perm2; gp.rank2=rank2; gp.hw2=hw2; gp.C2=C2; gp.dinv2=dinv2; gp.h2=h2;
  gp.perm3=perm3; gp.rank3=rank3; gp.hw3=hw3; gp.C3=C3; gp.dinv3=dinv3; gp.h3=h3;
  gp.hu2=hu2; gp.hu1=hu1; gp.hw4=hw4; gp.bnp=bnp; gp.bnq=bnq;

  void* kargs[] = { (void*)&gp };
  hipError_t err = hipLaunchCooperativeKernel((const void*)k_mega, dim3(GRID), dim3(TPB),
                                              kargs, 0, stream);
  if(err == hipSuccess) return;

  // ---------------- fallback: proven multi-kernel path ----------------
  hipMemsetAsync(zreg, 0, (size_t)(2*n0+64)*4, stream);
  const int gE = (E + TPB - 1) / TPB;
  k_count  <<<gE, TPB, 0, stream>>>(ei, E, cnt);
  k_scan<6><<<1, 1024, 0, stream>>>(cnt, n0, rowptr);
  k_fill   <<<gE, TPB, 0, stream>>>(ei, E, rowptr, fillc, colidx);
  k_mm_dinv<<<(n0*32+TPB-1)/TPB, TPB, 0, stream>>>(x, W0, nullptr, cnt, dinv0, hwd, n0, 3, 32);
  k_csr_gcn<32,true,true><<<(n0*32+TPB-1)/TPB, TPB, 0, stream>>>(rowptr, colidx, hwd, dinv0, b0, h0, n0, p0, score);
  k_pool_radix<6144><<<1, 1024, 0, stream>>>(score, h0, n0, K1, perm1, rank1, h1p);
  k_build_B1<<<K1, 256, 0, stream>>>(rowptr, colidx, perm1, rank1, K1,
                                     dinv1, rowbeg1, rowend1, col1, val1, cursor);
  k_mm_dinv<<<(K1*32+TPB-1)/TPB, TPB, 0, stream>>>(h1p, W1, dinv1, nullptr, nullptr, hwd, K1, 32, 32);
  k_spmm_gcn<true,true><<<(K1*32+TPB-1)/TPB, TPB, 0, stream>>>(rowbeg1, rowend1, col1, val1, hwd, dinv1, b1, h1, K1, p1, score);
  k_pool_radix<1216><<<1, 1024, 0, stream>>>(score, h1, K1, K2, perm2, rank2, h2p);
  k_twohop_sp<<<K2, 256, 0, stream>>>(rowbeg1, rowend1, col1, val1, perm2, rank2, C2, dinv2, K2);
  k_mm_dinv<<<(K2*32+TPB-1)/TPB, TPB, 0, stream>>>(h2p, W2, dinv2, nullptr, nullptr, hwd, K2, 32, 32);
  k_dgcn_row<true,true><<<K2, 256, 0, stream>>>(C2, hwd, dinv2, b2, h2, K2, p2, score);
  k_pool_radix<256><<<1, 1024, 0, stream>>>(score, h2, K2, K3, perm3, rank3, h3p);
  k_twohop_d3<<<K3, 256, 0, stream>>>(C2, K2, perm3, K3, C3, dinv3);
  k_mm_dinv<<<(K3*32+TPB-1)/TPB, TPB, 0, stream>>>(h3p, W3, dinv3, nullptr, nullptr, hwd, K3, 32, 32);
  k_dgcn_row<true,false><<<K3, 256, 0, stream>>>(C3, hwd, dinv3, b3, h3, K3, nullptr, nullptr);
  k_addup_mm<32><<<(K2*32+TPB-1)/TPB, TPB, 0, stream>>>(h2, h3, rank3, Wu0, dinv2, hwd, K2);
  k_dgcn_row<true,false><<<K2, 256, 0, stream>>>(C2, hwd, dinv2, bu0, hu2, K2, nullptr, nullptr);
  k_addup_mm<32><<<(K1*32+TPB-1)/TPB, TPB, 0, stream>>>(h1, hu2, rank2, Wu1, dinv1, hwd, K1);
  k_spmm_gcn<true,false><<<(K1*32+TPB-1)/TPB, TPB, 0, stream>>>(rowbeg1, rowend1, col1, val1, hwd, dinv1, bu1, hu1, K1, nullptr, nullptr);
  k_addup_mm<4><<<(n0*4+TPB-1)/TPB, TPB, 0, stream>>>(h0, hu1, rank1, Wu2, dinv0, hwd, n0);
  k_csr_gcn<4,false,false><<<(n0*4+TPB-1)/TPB, TPB, 0, stream>>>(rowptr, colidx, hwd, dinv0, bu2, out, n0, nullptr, nullptr);
  k_bn<<<1, 1024, 0, stream>>>(out, n0, bng, bnb);
}

// Round 7
// 260.409 us; speedup vs baseline: 2.7257x; 2.7257x over previous
//
#include <hip/hip_runtime.h>
#include <hip/hip_bf16.h>

#define TPB 256

__device__ __forceinline__ float block_sum_f(float v, float* fs){
  int tid = threadIdx.x, lane = tid & 63, w = tid >> 6;
  #pragma unroll
  for(int o = 32; o > 0; o >>= 1) v += __shfl_down(v, o, 64);
  __syncthreads();
  if(lane == 0) fs[w] = v;
  __syncthreads();
  return fs[0] + fs[1] + fs[2] + fs[3];
}

// ---------------- CSR build (level 0 adjacency) ----------------
__global__ void k_count(const int* __restrict__ ei, int E, int* __restrict__ cnt){
  int e = blockIdx.x*blockDim.x + threadIdx.x;
  if(e < E) atomicAdd(&cnt[ei[E + e]], 1);   // rows = dst = edge_index[1]
}

template<int IPT>
__global__ void k_scan(const int* __restrict__ cnt, int n, int* __restrict__ rowptr){
  int tid = threadIdx.x;
  int base = tid * IPT;
  int loc[IPT]; int s = 0;
  #pragma unroll
  for(int q = 0; q < IPT; ++q){ int i = base + q; int v = (i < n) ? cnt[i] : 0; s += v; loc[q] = s; }
  int lane = tid & 63, w = tid >> 6;
  int ss = s;
  #pragma unroll
  for(int o = 1; o < 64; o <<= 1){ int t = __shfl_up(ss, o, 64); if(lane >= o) ss += t; }
  __shared__ int wsum[16];
  if(lane == 63) wsum[w] = ss;
  __syncthreads();
  if(tid < 16){
    int t = wsum[tid];
    for(int o = 1; o < 16; o <<= 1){ int uu = __shfl_up(t, o, 64); if(tid >= o) t += uu; }
    wsum[tid] = t;
  }
  __syncthreads();
  int excl = ss - s + (w > 0 ? wsum[w-1] : 0);
  if(tid == 0) rowptr[0] = 0;
  #pragma unroll
  for(int q = 0; q < IPT; ++q){ int i = base + q; if(i < n) rowptr[i+1] = excl + loc[q]; }
}

__global__ void k_fill(const int* __restrict__ ei, int E, const int* __restrict__ rowptr,
                       int* __restrict__ fill, int* __restrict__ colidx){
  int e = blockIdx.x*blockDim.x + threadIdx.x;
  if(e >= E) return;
  int d = ei[E + e], s = ei[e];
  int p = rowptr[d] + atomicAdd(&fill[d], 1);
  colidx[p] = s;
}

// 3-channel degree-normalized aggregation: xa[i] = 2*di*x[i] + sum_j A_ij*dj*x[j]
__global__ void k_agg3(const float* __restrict__ x, const int* __restrict__ cnt,
                       const int* __restrict__ rowptr, const int* __restrict__ colidx,
                       float* __restrict__ dinv0, float* __restrict__ xa, int n){
  int i = blockIdx.x*blockDim.x + threadIdx.x;
  if(i >= n) return;
  float di = rsqrtf((float)cnt[i] + 2.0f);
  dinv0[i] = di;
  float s0 = 2.f*di*x[i*3], s1 = 2.f*di*x[i*3+1], s2 = 2.f*di*x[i*3+2];
  for(int q = rowptr[i]; q < rowptr[i+1]; ++q){
    int j = colidx[q];
    float dj = rsqrtf((float)cnt[j] + 2.0f);
    s0 += dj*x[j*3]; s1 += dj*x[j*3+1]; s2 += dj*x[j*3+2];
  }
  xa[i*3] = s0; xa[i*3+1] = s1; xa[i*3+2] = s2;
}

// GCN0 = relu(dinv0*(xa·W0)+b0), fused score(p0)
__global__ void k_gcn0(const float* __restrict__ xa, const float* __restrict__ W0,
                       const float* __restrict__ b0, const float* __restrict__ dinv0,
                       const float* __restrict__ p0, float* __restrict__ h0,
                       float* __restrict__ score, int n){
  int t = blockIdx.x*blockDim.x + threadIdx.x;
  if(t >= n*32) return;
  int i = t >> 5, c = t & 31;
  float y = dinv0[i]*(xa[i*3]*W0[c] + xa[i*3+1]*W0[32+c] + xa[i*3+2]*W0[64+c]) + b0[c];
  y = fmaxf(y, 0.f);
  h0[t] = y;
  float pv = p0[c]; float sd = y*pv, nn = pv*pv;
  #pragma unroll
  for(int o = 16; o > 0; o >>= 1){ sd += __shfl_xor(sd, o, 32); nn += __shfl_xor(nn, o, 32); }
  if(c == 0) score[i] = tanhf(sd / sqrtf(nn));
}

// exact top-k via 3-pass MSD radix-select (tie-aware, matches jax.lax.top_k's SET)
// epilogue: hw[i][c] = score[perm[i]] * (h[perm[i]]·W)[c]   (raw, dinv applied at gather)
template<int NMAX>
__global__ __launch_bounds__(1024)
void k_pool(const float* __restrict__ score, const float* __restrict__ h,
            const float* __restrict__ W, int n, int k,
            int* __restrict__ perm, int* __restrict__ rank, float* __restrict__ hw){
  __shared__ unsigned keys[NMAX];
  __shared__ int bins[2048];
  __shared__ int wsum[16];
  __shared__ unsigned s_prefix;
  __shared__ int s_rk, s_found, s_cntgt;
  int tid = threadIdx.x, lane = tid & 63, w = tid >> 6;
  for(int i = tid; i < n; i += 1024){
    rank[i] = -1;
    unsigned uu = __float_as_uint(score[i]);
    uu ^= (uu & 0x80000000u) ? 0xFFFFFFFFu : 0x80000000u;
    keys[i] = uu;
  }
  if(tid == 0){ s_prefix = 0u; s_rk = k; }
  __syncthreads();
  for(int pass = 0; pass < 3; ++pass){
    const int width = (pass < 2) ? 11 : 10;
    const int shift = (pass == 0) ? 21 : ((pass == 1) ? 10 : 0);
    const int nb = 1 << width;
    for(int b2 = tid; b2 < nb; b2 += 1024) bins[b2] = 0;
    __syncthreads();
    unsigned prefix = s_prefix;
    int rk = s_rk;
    const int hs = shift + width;
    for(int i = tid; i < n; i += 1024){
      unsigned kk = keys[i];
      bool match = (pass == 0) || ((kk >> hs) == (prefix >> hs));
      if(match) atomicAdd(&bins[(kk >> shift) & (nb-1)], 1);
    }
    __syncthreads();
    int ipt = (nb + 1023) >> 10;
    int loc0 = 0, loc1 = 0, s = 0;
    { int r = tid*ipt; int v = (r < nb) ? bins[nb-1-r] : 0; s += v; loc0 = s;
      if(ipt == 2){ int r2 = r+1; int v2 = (r2 < nb) ? bins[nb-1-r2] : 0; s += v2; loc1 = s; } }
    int ss = s;
    #pragma unroll
    for(int o = 1; o < 64; o <<= 1){ int t2 = __shfl_up(ss, o, 64); if(lane >= o) ss += t2; }
    if(lane == 63) wsum[w] = ss;
    __syncthreads();
    if(tid < 16){
      int t2 = wsum[tid];
      #pragma unroll
      for(int o = 1; o < 16; o <<= 1){ int u2 = __shfl_up(t2, o, 64); if(tid >= o) t2 += u2; }
      wsum[tid] = t2;
    }
    __syncthreads();
    int excl = ss - s + (w ? wsum[w-1] : 0);
    { int r = tid*ipt; if(r < nb) bins[nb-1-r] = excl + loc0;
      if(ipt == 2){ int r2 = r+1; if(r2 < nb) bins[nb-1-r2] = excl + loc1; } }
    __syncthreads();
    for(int b2 = tid; b2 < nb; b2 += 1024){
      int cge = bins[b2];
      int cgt = (b2+1 < nb) ? bins[b2+1] : 0;
      if(cge >= rk && cgt < rk){ s_found = b2; s_cntgt = cgt; }
    }
    __syncthreads();
    if(tid == 0){ s_prefix |= ((unsigned)s_found) << shift; s_rk -= s_cntgt; }
    __syncthreads();
  }
  unsigned T = s_prefix;
  int r = s_rk;
  int cgt_total = k - r;
  int CH = (n + 1023) >> 10;
  int base = tid*CH, c_gt = 0, c_eq = 0;
  for(int q = 0; q < CH; ++q){
    int i = base+q;
    if(i < n){ unsigned uu = keys[i]; c_gt += (uu > T); c_eq += (uu == T); }
  }
  int packed = c_gt*8192 + c_eq;
  int ss2 = packed;
  #pragma unroll
  for(int o = 1; o < 64; o <<= 1){ int t2 = __shfl_up(ss2, o, 64); if(lane >= o) ss2 += t2; }
  if(lane == 63) wsum[w] = ss2;
  __syncthreads();
  if(tid < 16){
    int t2 = wsum[tid];
    #pragma unroll
    for(int o = 1; o < 16; o <<= 1){ int u2 = __shfl_up(t2, o, 64); if(tid >= o) t2 += u2; }
    wsum[tid] = t2;
  }
  __syncthreads();
  int excl2 = ss2 - packed + (w ? wsum[w-1] : 0);
  int gt_before = excl2 / 8192, eq_before = excl2 % 8192;
  for(int q = 0; q < CH; ++q){
    int i = base+q;
    if(i >= n) continue;
    unsigned uu = keys[i];
    if(uu > T){ int pos = gt_before++; perm[pos] = i; rank[i] = pos; }
    else if(uu == T){
      int tr = eq_before++;
      if(tr < r){ int pos = cgt_total + tr; perm[pos] = i; rank[i] = pos; }
    }
  }
  __syncthreads();
  // epilogue: fused (pooled h)·W, raw (no dinv)
  for(int t = tid; t < k*32; t += 1024){
    int i = t >> 5, c = t & 31;
    int idx = perm[i];
    float sc = score[idx];
    const float* hr = h + (size_t)idx*32;
    float s = 0.f;
    #pragma unroll
    for(int d = 0; d < 32; ++d) s += hr[d]*W[d*32 + c];
    hw[t] = sc*s;
  }
}

// Build B1 = twohop0(A)[perm,perm] + I as CSR (block per pooled row, LDS row); emits dinv1.
__global__ __launch_bounds__(256)
void k_build_B1(const int* __restrict__ rowptr, const int* __restrict__ colidx,
                const int* __restrict__ perm1, const int* __restrict__ rank1, int K1,
                float* __restrict__ dinv1, int* __restrict__ rowbeg, int* __restrict__ rowend,
                int* __restrict__ col1, float* __restrict__ val1, int* __restrict__ cursor){
  __shared__ float row[1216];
  __shared__ int wsum[4];
  __shared__ float fs[4];
  __shared__ int s_base;
  int tid = threadIdx.x, lane = tid & 63, w = tid >> 6;
  int i = blockIdx.x;
  for(int j = tid; j < K1; j += 256) row[j] = 0.f;
  __syncthreads();
  int d = perm1[i];
  int b = rowptr[d], len = rowptr[d+1]-b;
  for(int p = tid; p < len; p += 256){
    int s = colidx[b+p]; int rs = rank1[s];
    if(rs >= 0) atomicAdd(&row[rs], 2.0f);          // 2A (exact int adds)
  }
  for(int ww = tid; ww < len*8; ww += 256){
    int p = ww >> 3, sub = ww & 7;
    int s = colidx[b+p];
    for(int q = rowptr[s]+sub, qe = rowptr[s+1]; q < qe; q += 8){
      int r2 = rank1[colidx[q]];
      if(r2 >= 0) atomicAdd(&row[r2], 1.0f);        // A^2 2-paths
    }
  }
  __syncthreads();
  if(tid == 0) row[i] = 0.f;                        // diag <- 0
  __syncthreads();
  float s = 0.f;
  for(int j = tid; j < K1; j += 256) s += row[j];
  float tot = block_sum_f(s, fs);
  if(tid == 0){ dinv1[i] = rsqrtf(tot + 2.0f); row[i] = 1.0f; }  // +I
  __syncthreads();
  int CH = (K1 + 255) >> 8;
  int base = tid*CH, cnt = 0;
  for(int q = 0; q < CH; ++q){ int j = base+q; if(j < K1 && row[j] != 0.f) ++cnt; }
  int ss = cnt;
  #pragma unroll
  for(int o = 1; o < 64; o <<= 1){ int t2 = __shfl_up(ss, o, 64); if(lane >= o) ss += t2; }
  if(lane == 63) wsum[w] = ss;
  __syncthreads();
  if(tid < 4){
    int t2 = wsum[tid];
    for(int o = 1; o < 4; o <<= 1){ int u2 = __shfl_up(t2, o, 64); if(tid >= o) t2 += u2; }
    wsum[tid] = t2;
  }
  __syncthreads();
  if(tid == 0) s_base = atomicAdd(cursor, wsum[3]);
  __syncthreads();
  int off = s_base + ss - cnt + (w ? wsum[w-1] : 0);
  for(int q = 0; q < CH; ++q){
    int j = base+q;
    if(j < K1 && row[j] != 0.f){ col1[off] = j; val1[off] = row[j]; ++off; }
  }
  if(tid == 0){ rowbeg[i] = s_base; rowend[i] = s_base + wsum[3]; }
}

// SpMM GCN, dinv applied at gather (hw is raw); optional score + rank init
template<bool RELU, bool SCORE>
__global__ void k_spmm(const int* __restrict__ rb, const int* __restrict__ re,
                       const int* __restrict__ ci, const float* __restrict__ cv,
                       const float* __restrict__ hw, const float* __restrict__ dinv,
                       const float* __restrict__ bias, float* __restrict__ out, int n,
                       const float* __restrict__ pvec, float* __restrict__ score,
                       int* __restrict__ rankinit){
  int t = blockIdx.x*blockDim.x + threadIdx.x;
  if(t >= n*32) return;
  int i = t >> 5, c = t & 31;
  float acc = dinv[i]*hw[t];
  for(int p = rb[i], e = re[i]; p < e; ++p){
    int j = ci[p];
    acc += cv[p]*dinv[j]*hw[j*32 + c];
  }
  float y = dinv[i]*acc + bias[c];
  y = RELU ? fmaxf(y, 0.f) : y;
  out[t] = y;
  if(SCORE){
    float pv = pvec[c];
    float sd = y*pv, nn = pv*pv;
    #pragma unroll
    for(int o = 16; o > 0; o >>= 1){ sd += __shfl_xor(sd, o, 32); nn += __shfl_xor(nn, o, 32); }
    if(c == 0) score[i] = tanhf(sd / sqrtf(nn));
  }
  if(rankinit && c == 0) rankinit[i] = -1;
}

// C2 = B1^2 [perm2][:,perm2], diag<-0, sparse path enumeration; emits dinv2
__global__ __launch_bounds__(256)
void k_twohop_sp(const int* __restrict__ rb, const int* __restrict__ re,
                 const int* __restrict__ ci, const float* __restrict__ cv,
                 const int* __restrict__ perm2, const int* __restrict__ rank2,
                 float* __restrict__ C2, float* __restrict__ dinv2, int K2){
  __shared__ float acc[256];
  __shared__ float fs[4];
  int i = blockIdx.x, tid = threadIdx.x;
  for(int j = tid; j < K2; j += 256) acc[j] = 0.f;
  __syncthreads();
  int qi = perm2[i];
  int b = rb[qi], len = re[qi]-b;
  for(int ww = tid; ww < len*8; ww += 256){
    int p = b + (ww >> 3), sub = ww & 7;
    int t = ci[p]; float v = cv[p];
    for(int q = rb[t] + sub, qe = re[t]; q < qe; q += 8){
      int j = rank2[ci[q]];
      if(j >= 0) atomicAdd(&acc[j], v*cv[q]);   // exact int adds
    }
  }
  __syncthreads();
  if(tid == 0) acc[i] = 0.f;
  __syncthreads();
  float s = 0.f;
  for(int j = tid; j < K2; j += 256) s += acc[j];
  float tot = block_sum_f(s, fs);
  if(tid == 0) dinv2[i] = rsqrtf(tot + 2.0f);
  for(int j = tid; j < K2; j += 256) C2[(size_t)i*K2 + j] = acc[j];
}

// dense GCN, block-per-row, dinv at gather; optional score + rank init
template<bool RELU, bool SCORE>
__global__ __launch_bounds__(256)
void k_dgcn(const float* __restrict__ C, const float* __restrict__ hw,
            const float* __restrict__ dinv, const float* __restrict__ bias,
            float* __restrict__ out, int n, const float* __restrict__ pvec,
            float* __restrict__ score, int* __restrict__ rankinit){
  __shared__ float sh[8][32];
  int i = blockIdx.x;
  int c = threadIdx.x & 31, sg = threadIdx.x >> 5;
  const float* row = C + (size_t)i*n;
  float a = 0.f;
  for(int t = sg; t < n; t += 8) a += row[t]*dinv[t]*hw[t*32 + c];
  sh[sg][c] = a;
  __syncthreads();
  if(sg == 0){
    float aa = sh[0][c]+sh[1][c]+sh[2][c]+sh[3][c]+sh[4][c]+sh[5][c]+sh[6][c]+sh[7][c];
    aa += 2.f*dinv[i]*hw[i*32 + c];
    float y = dinv[i]*aa + bias[c];
    y = RELU ? fmaxf(y, 0.f) : y;
    out[i*32 + c] = y;
    if(SCORE){
      float pv = pvec[c];
      float sd = y*pv, nn = pv*pv;
      #pragma unroll
      for(int o = 16; o > 0; o >>= 1){ sd += __shfl_xor(sd, o, 32); nn += __shfl_xor(nn, o, 32); }
      if(c == 0) score[i] = tanhf(sd / sqrtf(nn));
    }
    if(rankinit && c == 0) rankinit[i] = -1;
  }
}

// level-2 two-hop (fused gather): C3[i][j] = sum_t (C2[qi][t]+I)*(C2[t][qj]+I), diag<-0; dinv3
__global__ __launch_bounds__(256)
void k_twohop_d3(const float* __restrict__ C2, int n, const int* __restrict__ perm3,
                 int k, float* __restrict__ C3, float* __restrict__ dinv3){
  __shared__ float acc[4][64];
  int i = blockIdx.x, tid = threadIdx.x;
  int col = tid & 63, st = tid >> 6;
  int qi = perm3[i];
  int qj = (col < k) ? perm3[col] : 0;
  float a = 0.f;
  if(col < k){
    for(int tt = st; tt < n; tt += 4){
      float av = C2[(size_t)qi*n + tt] + ((tt == qi) ? 1.f : 0.f);
      float bv = C2[(size_t)tt*n + qj] + ((tt == qj) ? 1.f : 0.f);
      a += av * bv;
    }
  }
  acc[st][col] = a;
  __syncthreads();
  if(st == 0){
    float v = acc[0][col]+acc[1][col]+acc[2][col]+acc[3][col];
    if(col == i) v = 0.f;
    if(col < k) C3[(size_t)i*k + col] = v;
    float sv = (col < k) ? v : 0.f;
    #pragma unroll
    for(int o = 32; o > 0; o >>= 1) sv += __shfl_down(sv, o, 64);
    if(col == 0) dinv3[i] = rsqrtf(sv + 2.0f);
  }
}

// fused unpool-add + weight GEMM; DINV multiplies result by dinv[i]
template<int COUT, bool DINV>
__global__ void k_addup_mm(const float* __restrict__ base, const float* __restrict__ h,
                           const int* __restrict__ rank, const float* __restrict__ W,
                           const float* __restrict__ dinv, float* __restrict__ out, int n){
  int t = blockIdx.x*blockDim.x + threadIdx.x;
  if(t >= n*COUT) return;
  int i = t / COUT, c = t - i*COUT;
  int r = rank[i];
  const float* br = base + (size_t)i*32;
  const float* hr = h + (size_t)(r >= 0 ? r : 0)*32;
  float s = 0.f;
  #pragma unroll
  for(int d = 0; d < 32; ++d){
    float z = br[d] + ((r >= 0) ? hr[d] : 0.f);
    s += z * W[d*COUT + c];
  }
  out[t] = DINV ? (dinv[i]*s) : s;
}

// final CSR GCN (32->4 already applied; hw4 is dinv0*(z·Wu2)) + BN partial sums on col 0
__global__ void k_gcn_final(const int* __restrict__ rowptr, const int* __restrict__ colidx,
                            const float* __restrict__ hw4, const float* __restrict__ dinv0,
                            const float* __restrict__ bias, float* __restrict__ out, int n,
                            float* __restrict__ bnp, float* __restrict__ bnq){
  __shared__ float fs[4];
  int t = blockIdx.x*blockDim.x + threadIdx.x;
  float vs = 0.f, vq = 0.f;
  if(t < n*4){
    int i = t >> 2, c = t & 3;
    float acc = 2.f*hw4[t];
    for(int q = rowptr[i]; q < rowptr[i+1]; ++q) acc += hw4[colidx[q]*4 + c];
    float y = dinv0[i]*acc + bias[c];
    out[t] = y;
    if(c == 0){ vs = y; vq = y*y; }
  }
  float bs = block_sum_f(vs, fs);
  float bq = block_sum_f(vq, fs);
  if(threadIdx.x == 0){ bnp[blockIdx.x] = bs; bnq[blockIdx.x] = bq; }
}

// BN finish: each block redundantly reduces nblk partials, applies sigmoid to its slice
__global__ void k_bn_finish(float* __restrict__ out, int n, int nblk,
                            const float* __restrict__ bnp, const float* __restrict__ bnq,
                            const float* __restrict__ g, const float* __restrict__ b){
  __shared__ float fs[4];
  int tid = threadIdx.x;
  float sv = (tid < nblk) ? bnp[tid] : 0.f;
  float qv = (tid < nblk) ? bnq[tid] : 0.f;
  float tsum = block_sum_f(sv, fs);
  float tsq  = block_sum_f(qv, fs);
  float mean = tsum / n;
  float var  = tsq / n - mean*mean;
  float scale = g[0]*rsqrtf(var + 1e-5f);
  float beta  = b[0];
  for(int i = blockIdx.x*blockDim.x + tid; i < n; i += gridDim.x*blockDim.x){
    float r = scale*(out[i*4] - mean) + beta;
    out[i*4] = 1.f/(1.f + expf(-r));
  }
}

// =====================================================================
extern "C" void kernel_launch(void* const* d_in, const int* in_sizes, int n_in,
                              void* d_out, int out_size, void* d_ws, size_t ws_size,
                              hipStream_t stream){
  const float* x  =(const float*)d_in[0];
  const int*   ei =(const int*)  d_in[1];
  const float* W0 =(const float*)d_in[2];  const float* b0 =(const float*)d_in[3];
  const float* W1 =(const float*)d_in[4];  const float* b1 =(const float*)d_in[5];
  const float* W2 =(const float*)d_in[6];  const float* b2 =(const float*)d_in[7];
  const float* W3 =(const float*)d_in[8];  const float* b3 =(const float*)d_in[9];
  const float* p0 =(const float*)d_in[10];
  const float* p1 =(const float*)d_in[11];
  const float* p2 =(const float*)d_in[12];
  const float* Wu0=(const float*)d_in[13]; const float* bu0=(const float*)d_in[14];
  const float* Wu1=(const float*)d_in[15]; const float* bu1=(const float*)d_in[16];
  const float* Wu2=(const float*)d_in[17]; const float* bu2=(const float*)d_in[18];
  const float* bng=(const float*)d_in[19]; const float* bnb=(const float*)d_in[20];
  float* out = (float*)d_out;

  const int n0 = in_sizes[0] / 3;       // 6000
  const int E  = in_sizes[1] / 2;       // 96000
  const int K1 = (n0 + 4) / 5;          // 1200
  const int K2 = (K1 + 4) / 5;          // 240
  const int K3 = (K2 + 4) / 5;          // 48
  const int CAP1 = 512*1024;

  char* wsp = (char*)d_ws; size_t off = 0;
  auto alloc = [&](size_t bytes)->char*{
    char* p = wsp + off; off = (off + bytes + 255) & ~((size_t)255); return p;
  };

  // zeroed region: cnt | fill | cursor (single memset)
  int*   zreg   = (int*)  alloc((size_t)(2*n0+64)*4);
  int*   cnt    = zreg;
  int*   fillc  = zreg + n0;
  int*   cursor = zreg + 2*n0;
  int*   rowptr = (int*)  alloc((size_t)(n0+1)*4);
  int*   colidx = (int*)  alloc((size_t)E*4);
  float* dinv0  = (float*)alloc((size_t)n0*4);
  float* xa     = (float*)alloc((size_t)n0*3*4);
  float* h0     = (float*)alloc((size_t)n0*32*4);
  float* score  = (float*)alloc((size_t)n0*4);
  int*   perm1  = (int*)  alloc((size_t)K1*4);
  int*   rank1  = (int*)  alloc((size_t)n0*4);
  float* hw1    = (float*)alloc((size_t)K1*32*4);
  float* dinv1  = (float*)alloc((size_t)K1*4);
  int*   rowbeg1= (int*)  alloc((size_t)K1*4);
  int*   rowend1= (int*)  alloc((size_t)K1*4);
  int*   col1   = (int*)  alloc((size_t)CAP1*4);
  float* val1   = (float*)alloc((size_t)CAP1*4);
  float* h1     = (float*)alloc((size_t)K1*32*4);
  int*   perm2  = (int*)  alloc((size_t)K2*4);
  int*   rank2  = (int*)  alloc((size_t)K1*4);
  float* hw2    = (float*)alloc((size_t)K2*32*4);
  float* C2     = (float*)alloc((size_t)K2*K2*4);
  float* dinv2  = (float*)alloc((size_t)K2*4);
  float* h2     = (float*)alloc((size_t)K2*32*4);
  int*   perm3  = (int*)  alloc((size_t)K3*4);
  int*   rank3  = (int*)  alloc((size_t)K2*4);
  float* hw3    = (float*)alloc((size_t)K3*32*4);
  float* C3     = (float*)alloc((size_t)K3*K3*4);
  float* dinv3  = (float*)alloc((size_t)K3*4);
  float* h3     = (float*)alloc((size_t)K3*32*4);
  float* hu2    = (float*)alloc((size_t)K2*32*4);
  float* hu1    = (float*)alloc((size_t)K1*32*4);
  float* hw4    = (float*)alloc((size_t)n0*4*4);
  float* bnp    = (float*)alloc((size_t)128*4);
  float* bnq    = (float*)alloc((size_t)128*4);

  hipMemsetAsync(zreg, 0, (size_t)(2*n0+64)*4, stream);

  const int gE  = (E + TPB - 1) / TPB;
  const int gBN = (n0*4 + TPB - 1) / TPB;   // 94 blocks (<=128 partials)
  // ---- CSR0 ----
  k_count  <<<gE, TPB, 0, stream>>>(ei, E, cnt);
  k_scan<6><<<1, 1024, 0, stream>>>(cnt, n0, rowptr);
  k_fill   <<<gE, TPB, 0, stream>>>(ei, E, rowptr, fillc, colidx);
  // ---- GCN0: 3ch-aggregate then fused 3->32 GEMM + score ----
  k_agg3<<<(n0+TPB-1)/TPB, TPB, 0, stream>>>(x, cnt, rowptr, colidx, dinv0, xa, n0);
  k_gcn0<<<(n0*32+TPB-1)/TPB, TPB, 0, stream>>>(xa, W0, b0, dinv0, p0, h0, score, n0);
  // ---- pool1 (+ hw1 = sc*(h0[perm]·W1) epilogue) ----
  k_pool<6144><<<1, 1024, 0, stream>>>(score, h0, W1, n0, K1, perm1, rank1, hw1);
  // ---- B1 CSR + dinv1 ----
  k_build_B1<<<K1, 256, 0, stream>>>(rowptr, colidx, perm1, rank1, K1,
                                     dinv1, rowbeg1, rowend1, col1, val1, cursor);
  // ---- GCN1 sparse (dinv at gather) + score + rank2 init ----
  k_spmm<true,true><<<(K1*32+TPB-1)/TPB, TPB, 0, stream>>>(rowbeg1, rowend1, col1, val1,
                                                           hw1, dinv1, b1, h1, K1, p1, score, rank2);
  // ---- pool2 (+ hw2 epilogue) ----
  k_pool<1216><<<1, 1024, 0, stream>>>(score, h1, W2, K1, K2, perm2, rank2, hw2);
  // ---- two-hop level1 -> C2 + dinv2 ----
  k_twohop_sp<<<K2, 256, 0, stream>>>(rowbeg1, rowend1, col1, val1, perm2, rank2, C2, dinv2, K2);
  // ---- GCN2 dense + score + rank3 init ----
  k_dgcn<true,true><<<K2, 256, 0, stream>>>(C2, hw2, dinv2, b2, h2, K2, p2, score, rank3);
  // ---- pool3 (+ hw3 epilogue) ----
  k_pool<256><<<1, 1024, 0, stream>>>(score, h2, W3, K2, K3, perm3, rank3, hw3);
  // ---- two-hop level2 -> C3 + dinv3 ----
  k_twohop_d3<<<K3, 256, 0, stream>>>(C2, K2, perm3, K3, C3, dinv3);
  // ---- GCN3 dense -> h3 ----
  k_dgcn<true,false><<<K3, 256, 0, stream>>>(C3, hw3, dinv3, b3, h3, K3, nullptr, nullptr, nullptr);
  // ---- up0 ----
  k_addup_mm<32,false><<<(K2*32+TPB-1)/TPB, TPB, 0, stream>>>(h2, h3, rank3, Wu0, nullptr, hw2, K2);
  k_dgcn<true,false><<<K2, 256, 0, stream>>>(C2, hw2, dinv2, bu0, hu2, K2, nullptr, nullptr, nullptr);
  // ---- up1 ----
  k_addup_mm<32,false><<<(K1*32+TPB-1)/TPB, TPB, 0, stream>>>(h1, hu2, rank2, Wu1, nullptr, hw1, K1);
  k_spmm<true,false><<<(K1*32+TPB-1)/TPB, TPB, 0, stream>>>(rowbeg1, rowend1, col1, val1,
                                                            hw1, dinv1, bu1, hu1, K1, nullptr, nullptr, nullptr);
  // ---- up2 (32->4, dinv0 folded) + final CSR GCN + BN ----
  k_addup_mm<4,true><<<(n0*4+TPB-1)/TPB, TPB, 0, stream>>>(h0, hu1, rank1, Wu2, dinv0, hw4, n0);
  k_gcn_final<<<gBN, TPB, 0, stream>>>(rowptr, colidx, hw4, dinv0, bu2, out, n0, bnp, bnq);
  k_bn_finish<<<24, TPB, 0, stream>>>(out, n0, gBN, bnp, bnq, bng, bnb);
}

// Round 8
// 213.994 us; speedup vs baseline: 3.3169x; 1.2169x over previous
//
#include <hip/hip_runtime.h>
#include <hip/hip_bf16.h>

#define TPB 256

__device__ __forceinline__ float block_sum_f(float v, float* fs){
  int tid = threadIdx.x, lane = tid & 63, w = tid >> 6;
  #pragma unroll
  for(int o = 32; o > 0; o >>= 1) v += __shfl_down(v, o, 64);
  __syncthreads();
  if(lane == 0) fs[w] = v;
  __syncthreads();
  return fs[0] + fs[1] + fs[2] + fs[3];
}

// ---------------- CSR build (level 0 adjacency) ----------------
__global__ void k_count(const int* __restrict__ ei, int E, int* __restrict__ cnt){
  int e = blockIdx.x*blockDim.x + threadIdx.x;
  if(e < E) atomicAdd(&cnt[ei[E + e]], 1);   // rows = dst = edge_index[1]
}

template<int IPT>
__global__ void k_scan(const int* __restrict__ cnt, int n, int* __restrict__ rowptr){
  int tid = threadIdx.x;
  int base = tid * IPT;
  int loc[IPT]; int s = 0;
  #pragma unroll
  for(int q = 0; q < IPT; ++q){ int i = base + q; int v = (i < n) ? cnt[i] : 0; s += v; loc[q] = s; }
  int lane = tid & 63, w = tid >> 6;
  int ss = s;
  #pragma unroll
  for(int o = 1; o < 64; o <<= 1){ int t = __shfl_up(ss, o, 64); if(lane >= o) ss += t; }
  __shared__ int wsum[16];
  if(lane == 63) wsum[w] = ss;
  __syncthreads();
  if(tid < 16){
    int t = wsum[tid];
    for(int o = 1; o < 16; o <<= 1){ int uu = __shfl_up(t, o, 64); if(tid >= o) t += uu; }
    wsum[tid] = t;
  }
  __syncthreads();
  int excl = ss - s + (w > 0 ? wsum[w-1] : 0);
  if(tid == 0) rowptr[0] = 0;
  #pragma unroll
  for(int q = 0; q < IPT; ++q){ int i = base + q; if(i < n) rowptr[i+1] = excl + loc[q]; }
}

__global__ void k_fill(const int* __restrict__ ei, int E, const int* __restrict__ rowptr,
                       int* __restrict__ fill, int* __restrict__ colidx){
  int e = blockIdx.x*blockDim.x + threadIdx.x;
  if(e >= E) return;
  int d = ei[E + e], s = ei[e];
  int p = rowptr[d] + atomicAdd(&fill[d], 1);
  colidx[p] = s;
}

// 3-channel degree-normalized aggregation: xa[i] = 2*di*x[i] + sum_j A_ij*dj*x[j]
__global__ void k_agg3(const float* __restrict__ x, const int* __restrict__ cnt,
                       const int* __restrict__ rowptr, const int* __restrict__ colidx,
                       float* __restrict__ dinv0, float* __restrict__ xa, int n){
  int i = blockIdx.x*blockDim.x + threadIdx.x;
  if(i >= n) return;
  float di = rsqrtf((float)cnt[i] + 2.0f);
  dinv0[i] = di;
  float s0 = 2.f*di*x[i*3], s1 = 2.f*di*x[i*3+1], s2 = 2.f*di*x[i*3+2];
  for(int q = rowptr[i]; q < rowptr[i+1]; ++q){
    int j = colidx[q];
    float dj = rsqrtf((float)cnt[j] + 2.0f);
    s0 += dj*x[j*3]; s1 += dj*x[j*3+1]; s2 += dj*x[j*3+2];
  }
  xa[i*3] = s0; xa[i*3+1] = s1; xa[i*3+2] = s2;
}

// GCN0 = relu(dinv0*(xa·W0)+b0), fused score(p0)
__global__ void k_gcn0(const float* __restrict__ xa, const float* __restrict__ W0,
                       const float* __restrict__ b0, const float* __restrict__ dinv0,
                       const float* __restrict__ p0, float* __restrict__ h0,
                       float* __restrict__ score, int n){
  int t = blockIdx.x*blockDim.x + threadIdx.x;
  if(t >= n*32) return;
  int i = t >> 5, c = t & 31;
  float y = dinv0[i]*(xa[i*3]*W0[c] + xa[i*3+1]*W0[32+c] + xa[i*3+2]*W0[64+c]) + b0[c];
  y = fmaxf(y, 0.f);
  h0[t] = y;
  float pv = p0[c]; float sd = y*pv, nn = pv*pv;
  #pragma unroll
  for(int o = 16; o > 0; o >>= 1){ sd += __shfl_xor(sd, o, 32); nn += __shfl_xor(nn, o, 32); }
  if(c == 0) score[i] = tanhf(sd / sqrtf(nn));
}

// SELECT-ONLY top-k: 3-pass MSD radix-select on 32-bit mapped scores; tie-aware
// deterministic compaction (ties take lowest indices) — same SET as jax.lax.top_k.
template<int NMAX>
__global__ __launch_bounds__(1024)
void k_pool(const float* __restrict__ score, int n, int k,
            int* __restrict__ perm, int* __restrict__ rank){
  __shared__ unsigned keys[NMAX];
  __shared__ int bins[2048];
  __shared__ int wsum[16];
  __shared__ unsigned s_prefix;
  __shared__ int s_rk, s_found, s_cntgt;
  int tid = threadIdx.x, lane = tid & 63, w = tid >> 6;
  for(int i = tid; i < n; i += 1024){
    rank[i] = -1;
    unsigned uu = __float_as_uint(score[i]);
    uu ^= (uu & 0x80000000u) ? 0xFFFFFFFFu : 0x80000000u;
    keys[i] = uu;
  }
  if(tid == 0){ s_prefix = 0u; s_rk = k; }
  __syncthreads();
  for(int pass = 0; pass < 3; ++pass){
    const int width = (pass < 2) ? 11 : 10;
    const int shift = (pass == 0) ? 21 : ((pass == 1) ? 10 : 0);
    const int nb = 1 << width;
    for(int b2 = tid; b2 < nb; b2 += 1024) bins[b2] = 0;
    __syncthreads();
    unsigned prefix = s_prefix;
    int rk = s_rk;
    const int hs = shift + width;
    for(int i = tid; i < n; i += 1024){
      unsigned kk = keys[i];
      bool match = (pass == 0) || ((kk >> hs) == (prefix >> hs));
      if(match) atomicAdd(&bins[(kk >> shift) & (nb-1)], 1);
    }
    __syncthreads();
    int ipt = (nb + 1023) >> 10;
    int loc0 = 0, loc1 = 0, s = 0;
    { int r = tid*ipt; int v = (r < nb) ? bins[nb-1-r] : 0; s += v; loc0 = s;
      if(ipt == 2){ int r2 = r+1; int v2 = (r2 < nb) ? bins[nb-1-r2] : 0; s += v2; loc1 = s; } }
    int ss = s;
    #pragma unroll
    for(int o = 1; o < 64; o <<= 1){ int t2 = __shfl_up(ss, o, 64); if(lane >= o) ss += t2; }
    if(lane == 63) wsum[w] = ss;
    __syncthreads();
    if(tid < 16){
      int t2 = wsum[tid];
      #pragma unroll
      for(int o = 1; o < 16; o <<= 1){ int u2 = __shfl_up(t2, o, 64); if(tid >= o) t2 += u2; }
      wsum[tid] = t2;
    }
    __syncthreads();
    int excl = ss - s + (w ? wsum[w-1] : 0);
    { int r = tid*ipt; if(r < nb) bins[nb-1-r] = excl + loc0;
      if(ipt == 2){ int r2 = r+1; if(r2 < nb) bins[nb-1-r2] = excl + loc1; } }
    __syncthreads();
    for(int b2 = tid; b2 < nb; b2 += 1024){
      int cge = bins[b2];
      int cgt = (b2+1 < nb) ? bins[b2+1] : 0;
      if(cge >= rk && cgt < rk){ s_found = b2; s_cntgt = cgt; }
    }
    __syncthreads();
    if(tid == 0){ s_prefix |= ((unsigned)s_found) << shift; s_rk -= s_cntgt; }
    __syncthreads();
  }
  unsigned T = s_prefix;
  int r = s_rk;
  int cgt_total = k - r;
  int CH = (n + 1023) >> 10;
  int base = tid*CH, c_gt = 0, c_eq = 0;
  for(int q = 0; q < CH; ++q){
    int i = base+q;
    if(i < n){ unsigned uu = keys[i]; c_gt += (uu > T); c_eq += (uu == T); }
  }
  int packed = c_gt*8192 + c_eq;
  int ss2 = packed;
  #pragma unroll
  for(int o = 1; o < 64; o <<= 1){ int t2 = __shfl_up(ss2, o, 64); if(lane >= o) ss2 += t2; }
  if(lane == 63) wsum[w] = ss2;
  __syncthreads();
  if(tid < 16){
    int t2 = wsum[tid];
    #pragma unroll
    for(int o = 1; o < 16; o <<= 1){ int u2 = __shfl_up(t2, o, 64); if(tid >= o) t2 += u2; }
    wsum[tid] = t2;
  }
  __syncthreads();
  int excl2 = ss2 - packed + (w ? wsum[w-1] : 0);
  int gt_before = excl2 / 8192, eq_before = excl2 % 8192;
  for(int q = 0; q < CH; ++q){
    int i = base+q;
    if(i >= n) continue;
    unsigned uu = keys[i];
    if(uu > T){ int pos = gt_before++; perm[pos] = i; rank[i] = pos; }
    else if(uu == T){
      int tr = eq_before++;
      if(tr < r){ int pos = cgt_total + tr; perm[pos] = i; rank[i] = pos; }
    }
  }
}

// full-grid fused pooled-gather + weight GEMM: hw[i][c] = score[perm[i]]*(h[perm[i]]·W)[c]
__global__ void k_gather_mm(const float* __restrict__ h, const float* __restrict__ score,
                            const int* __restrict__ perm, const float* __restrict__ W,
                            float* __restrict__ hw, int k){
  int t = blockIdx.x*blockDim.x + threadIdx.x;
  if(t >= k*32) return;
  int i = t >> 5, c = t & 31;
  int idx = perm[i];
  float sc = score[idx];
  const float* hr = h + (size_t)idx*32;
  float s = 0.f;
  #pragma unroll
  for(int d = 0; d < 32; ++d) s += hr[d]*W[d*32 + c];
  hw[t] = sc*s;
}

// Build B1 = twohop0(A)[perm,perm] + I as CSR (block per pooled row, LDS row); emits dinv1.
__global__ __launch_bounds__(256)
void k_build_B1(const int* __restrict__ rowptr, const int* __restrict__ colidx,
                const int* __restrict__ perm1, const int* __restrict__ rank1, int K1,
                float* __restrict__ dinv1, int* __restrict__ rowbeg, int* __restrict__ rowend,
                int* __restrict__ col1, float* __restrict__ val1, int* __restrict__ cursor){
  __shared__ float row[1216];
  __shared__ int wsum[4];
  __shared__ float fs[4];
  __shared__ int s_base;
  int tid = threadIdx.x, lane = tid & 63, w = tid >> 6;
  int i = blockIdx.x;
  for(int j = tid; j < K1; j += 256) row[j] = 0.f;
  __syncthreads();
  int d = perm1[i];
  int b = rowptr[d], len = rowptr[d+1]-b;
  for(int p = tid; p < len; p += 256){
    int s = colidx[b+p]; int rs = rank1[s];
    if(rs >= 0) atomicAdd(&row[rs], 2.0f);          // 2A (exact int adds)
  }
  for(int ww = tid; ww < len*8; ww += 256){
    int p = ww >> 3, sub = ww & 7;
    int s = colidx[b+p];
    for(int q = rowptr[s]+sub, qe = rowptr[s+1]; q < qe; q += 8){
      int r2 = rank1[colidx[q]];
      if(r2 >= 0) atomicAdd(&row[r2], 1.0f);        // A^2 2-paths
    }
  }
  __syncthreads();
  if(tid == 0) row[i] = 0.f;                        // diag <- 0
  __syncthreads();
  float s = 0.f;
  for(int j = tid; j < K1; j += 256) s += row[j];
  float tot = block_sum_f(s, fs);
  if(tid == 0){ dinv1[i] = rsqrtf(tot + 2.0f); row[i] = 1.0f; }  // +I
  __syncthreads();
  int CH = (K1 + 255) >> 8;
  int base = tid*CH, cnt = 0;
  for(int q = 0; q < CH; ++q){ int j = base+q; if(j < K1 && row[j] != 0.f) ++cnt; }
  int ss = cnt;
  #pragma unroll
  for(int o = 1; o < 64; o <<= 1){ int t2 = __shfl_up(ss, o, 64); if(lane >= o) ss += t2; }
  if(lane == 63) wsum[w] = ss;
  __syncthreads();
  if(tid < 4){
    int t2 = wsum[tid];
    for(int o = 1; o < 4; o <<= 1){ int u2 = __shfl_up(t2, o, 64); if(tid >= o) t2 += u2; }
    wsum[tid] = t2;
  }
  __syncthreads();
  if(tid == 0) s_base = atomicAdd(cursor, wsum[3]);
  __syncthreads();
  int off = s_base + ss - cnt + (w ? wsum[w-1] : 0);
  for(int q = 0; q < CH; ++q){
    int j = base+q;
    if(j < K1 && row[j] != 0.f){ col1[off] = j; val1[off] = row[j]; ++off; }
  }
  if(tid == 0){ rowbeg[i] = s_base; rowend[i] = s_base + wsum[3]; }
}

// SpMM GCN, dinv applied at gather (hw is raw); optional score
template<bool RELU, bool SCORE>
__global__ void k_spmm(const int* __restrict__ rb, const int* __restrict__ re,
                       const int* __restrict__ ci, const float* __restrict__ cv,
                       const float* __restrict__ hw, const float* __restrict__ dinv,
                       const float* __restrict__ bias, float* __restrict__ out, int n,
                       const float* __restrict__ pvec, float* __restrict__ score){
  int t = blockIdx.x*blockDim.x + threadIdx.x;
  if(t >= n*32) return;
  int i = t >> 5, c = t & 31;
  float acc = dinv[i]*hw[t];
  for(int p = rb[i], e = re[i]; p < e; ++p){
    int j = ci[p];
    acc += cv[p]*dinv[j]*hw[j*32 + c];
  }
  float y = dinv[i]*acc + bias[c];
  y = RELU ? fmaxf(y, 0.f) : y;
  out[t] = y;
  if(SCORE){
    float pv = pvec[c];
    float sd = y*pv, nn = pv*pv;
    #pragma unroll
    for(int o = 16; o > 0; o >>= 1){ sd += __shfl_xor(sd, o, 32); nn += __shfl_xor(nn, o, 32); }
    if(c == 0) score[i] = tanhf(sd / sqrtf(nn));
  }
}

// C2 = B1^2 [perm2][:,perm2], diag<-0, sparse path enumeration; emits dinv2
__global__ __launch_bounds__(256)
void k_twohop_sp(const int* __restrict__ rb, const int* __restrict__ re,
                 const int* __restrict__ ci, const float* __restrict__ cv,
                 const int* __restrict__ perm2, const int* __restrict__ rank2,
                 float* __restrict__ C2, float* __restrict__ dinv2, int K2){
  __shared__ float acc[256];
  __shared__ float fs[4];
  int i = blockIdx.x, tid = threadIdx.x;
  for(int j = tid; j < K2; j += 256) acc[j] = 0.f;
  __syncthreads();
  int qi = perm2[i];
  int b = rb[qi], len = re[qi]-b;
  for(int ww = tid; ww < len*8; ww += 256){
    int p = b + (ww >> 3), sub = ww & 7;
    int t = ci[p]; float v = cv[p];
    for(int q = rb[t] + sub, qe = re[t]; q < qe; q += 8){
      int j = rank2[ci[q]];
      if(j >= 0) atomicAdd(&acc[j], v*cv[q]);   // exact int adds
    }
  }
  __syncthreads();
  if(tid == 0) acc[i] = 0.f;
  __syncthreads();
  float s = 0.f;
  for(int j = tid; j < K2; j += 256) s += acc[j];
  float tot = block_sum_f(s, fs);
  if(tid == 0) dinv2[i] = rsqrtf(tot + 2.0f);
  for(int j = tid; j < K2; j += 256) C2[(size_t)i*K2 + j] = acc[j];
}

// dense GCN, block-per-row, dinv at gather; optional score
template<bool RELU, bool SCORE>
__global__ __launch_bounds__(256)
void k_dgcn(const float* __restrict__ C, const float* __restrict__ hw,
            const float* __restrict__ dinv, const float* __restrict__ bias,
            float* __restrict__ out, int n, const float* __restrict__ pvec,
            float* __restrict__ score){
  __shared__ float sh[8][32];
  int i = blockIdx.x;
  int c = threadIdx.x & 31, sg = threadIdx.x >> 5;
  const float* row = C + (size_t)i*n;
  float a = 0.f;
  for(int t = sg; t < n; t += 8) a += row[t]*dinv[t]*hw[t*32 + c];
  sh[sg][c] = a;
  __syncthreads();
  if(sg == 0){
    float aa = sh[0][c]+sh[1][c]+sh[2][c]+sh[3][c]+sh[4][c]+sh[5][c]+sh[6][c]+sh[7][c];
    aa += 2.f*dinv[i]*hw[i*32 + c];
    float y = dinv[i]*aa + bias[c];
    y = RELU ? fmaxf(y, 0.f) : y;
    out[i*32 + c] = y;
    if(SCORE){
      float pv = pvec[c];
      float sd = y*pv, nn = pv*pv;
      #pragma unroll
      for(int o = 16; o > 0; o >>= 1){ sd += __shfl_xor(sd, o, 32); nn += __shfl_xor(nn, o, 32); }
      if(c == 0) score[i] = tanhf(sd / sqrtf(nn));
    }
  }
}

// level-2 two-hop (fused gather): C3[i][j] = sum_t (C2[qi][t]+I)*(C2[t][qj]+I), diag<-0; dinv3
__global__ __launch_bounds__(256)
void k_twohop_d3(const float* __restrict__ C2, int n, const int* __restrict__ perm3,
                 int k, float* __restrict__ C3, float* __restrict__ dinv3){
  __shared__ float acc[4][64];
  int i = blockIdx.x, tid = threadIdx.x;
  int col = tid & 63, st = tid >> 6;
  int qi = perm3[i];
  int qj = (col < k) ? perm3[col] : 0;
  float a = 0.f;
  if(col < k){
    for(int tt = st; tt < n; tt += 4){
      float av = C2[(size_t)qi*n + tt] + ((tt == qi) ? 1.f : 0.f);
      float bv = C2[(size_t)tt*n + qj] + ((tt == qj) ? 1.f : 0.f);
      a += av * bv;
    }
  }
  acc[st][col] = a;
  __syncthreads();
  if(st == 0){
    float v = acc[0][col]+acc[1][col]+acc[2][col]+acc[3][col];
    if(col == i) v = 0.f;
    if(col < k) C3[(size_t)i*k + col] = v;
    float sv = (col < k) ? v : 0.f;
    #pragma unroll
    for(int o = 32; o > 0; o >>= 1) sv += __shfl_down(sv, o, 64);
    if(col == 0) dinv3[i] = rsqrtf(sv + 2.0f);
  }
}

// fused unpool-add + weight GEMM; DINV multiplies result by dinv[i]
template<int COUT, bool DINV>
__global__ void k_addup_mm(const float* __restrict__ base, const float* __restrict__ h,
                           const int* __restrict__ rank, const float* __restrict__ W,
                           const float* __restrict__ dinv, float* __restrict__ out, int n){
  int t = blockIdx.x*blockDim.x + threadIdx.x;
  if(t >= n*COUT) return;
  int i = t / COUT, c = t - i*COUT;
  int r = rank[i];
  const float* br = base + (size_t)i*32;
  const float* hr = h + (size_t)(r >= 0 ? r : 0)*32;
  float s = 0.f;
  #pragma unroll
  for(int d = 0; d < 32; ++d){
    float z = br[d] + ((r >= 0) ? hr[d] : 0.f);
    s += z * W[d*COUT + c];
  }
  out[t] = DINV ? (dinv[i]*s) : s;
}

// final CSR GCN (32->4 already applied; hw4 is dinv0*(z·Wu2)) + BN partial sums on col 0
__global__ void k_gcn_final(const int* __restrict__ rowptr, const int* __restrict__ colidx,
                            const float* __restrict__ hw4, const float* __restrict__ dinv0,
                            const float* __restrict__ bias, float* __restrict__ out, int n,
                            float* __restrict__ bnp, float* __restrict__ bnq){
  __shared__ float fs[4];
  int t = blockIdx.x*blockDim.x + threadIdx.x;
  float vs = 0.f, vq = 0.f;
  if(t < n*4){
    int i = t >> 2, c = t & 3;
    float acc = 2.f*hw4[t];
    for(int q = rowptr[i]; q < rowptr[i+1]; ++q) acc += hw4[colidx[q]*4 + c];
    float y = dinv0[i]*acc + bias[c];
    out[t] = y;
    if(c == 0){ vs = y; vq = y*y; }
  }
  float bs = block_sum_f(vs, fs);
  float bq = block_sum_f(vq, fs);
  if(threadIdx.x == 0){ bnp[blockIdx.x] = bs; bnq[blockIdx.x] = bq; }
}

// BN finish: each block redundantly reduces nblk partials, applies sigmoid to its slice
__global__ void k_bn_finish(float* __restrict__ out, int n, int nblk,
                            const float* __restrict__ bnp, const float* __restrict__ bnq,
                            const float* __restrict__ g, const float* __restrict__ b){
  __shared__ float fs[4];
  int tid = threadIdx.x;
  float sv = (tid < nblk) ? bnp[tid] : 0.f;
  float qv = (tid < nblk) ? bnq[tid] : 0.f;
  float tsum = block_sum_f(sv, fs);
  float tsq  = block_sum_f(qv, fs);
  float mean = tsum / n;
  float var  = tsq / n - mean*mean;
  float scale = g[0]*rsqrtf(var + 1e-5f);
  float beta  = b[0];
  for(int i = blockIdx.x*blockDim.x + tid; i < n; i += gridDim.x*blockDim.x){
    float r = scale*(out[i*4] - mean) + beta;
    out[i*4] = 1.f/(1.f + expf(-r));
  }
}

// =====================================================================
extern "C" void kernel_launch(void* const* d_in, const int* in_sizes, int n_in,
                              void* d_out, int out_size, void* d_ws, size_t ws_size,
                              hipStream_t stream){
  const float* x  =(const float*)d_in[0];
  const int*   ei =(const int*)  d_in[1];
  const float* W0 =(const float*)d_in[2];  const float* b0 =(const float*)d_in[3];
  const float* W1 =(const float*)d_in[4];  const float* b1 =(const float*)d_in[5];
  const float* W2 =(const float*)d_in[6];  const float* b2 =(const float*)d_in[7];
  const float* W3 =(const float*)d_in[8];  const float* b3 =(const float*)d_in[9];
  const float* p0 =(const float*)d_in[10];
  const float* p1 =(const float*)d_in[11];
  const float* p2 =(const float*)d_in[12];
  const float* Wu0=(const float*)d_in[13]; const float* bu0=(const float*)d_in[14];
  const float* Wu1=(const float*)d_in[15]; const float* bu1=(const float*)d_in[16];
  const float* Wu2=(const float*)d_in[17]; const float* bu2=(const float*)d_in[18];
  const float* bng=(const float*)d_in[19]; const float* bnb=(const float*)d_in[20];
  float* out = (float*)d_out;

  const int n0 = in_sizes[0] / 3;       // 6000
  const int E  = in_sizes[1] / 2;       // 96000
  const int K1 = (n0 + 4) / 5;          // 1200
  const int K2 = (K1 + 4) / 5;          // 240
  const int K3 = (K2 + 4) / 5;          // 48
  const int CAP1 = 512*1024;

  char* wsp = (char*)d_ws; size_t off = 0;
  auto alloc = [&](size_t bytes)->char*{
    char* p = wsp + off; off = (off + bytes + 255) & ~((size_t)255); return p;
  };

  // zeroed region: cnt | fill | cursor (single memset)
  int*   zreg   = (int*)  alloc((size_t)(2*n0+64)*4);
  int*   cnt    = zreg;
  int*   fillc  = zreg + n0;
  int*   cursor = zreg + 2*n0;
  int*   rowptr = (int*)  alloc((size_t)(n0+1)*4);
  int*   colidx = (int*)  alloc((size_t)E*4);
  float* dinv0  = (float*)alloc((size_t)n0*4);
  float* xa     = (float*)alloc((size_t)n0*3*4);
  float* h0     = (float*)alloc((size_t)n0*32*4);
  float* score  = (float*)alloc((size_t)n0*4);
  int*   perm1  = (int*)  alloc((size_t)K1*4);
  int*   rank1  = (int*)  alloc((size_t)n0*4);
  float* hw1    = (float*)alloc((size_t)K1*32*4);
  float* dinv1  = (float*)alloc((size_t)K1*4);
  int*   rowbeg1= (int*)  alloc((size_t)K1*4);
  int*   rowend1= (int*)  alloc((size_t)K1*4);
  int*   col1   = (int*)  alloc((size_t)CAP1*4);
  float* val1   = (float*)alloc((size_t)CAP1*4);
  float* h1     = (float*)alloc((size_t)K1*32*4);
  int*   perm2  = (int*)  alloc((size_t)K2*4);
  int*   rank2  = (int*)  alloc((size_t)K1*4);
  float* hw2    = (float*)alloc((size_t)K2*32*4);
  float* C2     = (float*)alloc((size_t)K2*K2*4);
  float* dinv2  = (float*)alloc((size_t)K2*4);
  float* h2     = (float*)alloc((size_t)K2*32*4);
  int*   perm3  = (int*)  alloc((size_t)K3*4);
  int*   rank3  = (int*)  alloc((size_t)K2*4);
  float* hw3    = (float*)alloc((size_t)K3*32*4);
  float* C3     = (float*)alloc((size_t)K3*K3*4);
  float* dinv3  = (float*)alloc((size_t)K3*4);
  float* h3     = (float*)alloc((size_t)K3*32*4);
  float* hu2    = (float*)alloc((size_t)K2*32*4);
  float* hu1    = (float*)alloc((size_t)K1*32*4);
  float* hw4    = (float*)alloc((size_t)n0*4*4);
  float* bnp    = (float*)alloc((size_t)128*4);
  float* bnq    = (float*)alloc((size_t)128*4);

  hipMemsetAsync(zreg, 0, (size_t)(2*n0+64)*4, stream);

  const int gE  = (E + TPB - 1) / TPB;
  const int gBN = (n0*4 + TPB - 1) / TPB;   // 94 blocks (<=128 partials)
  // ---- CSR0 ----
  k_count  <<<gE, TPB, 0, stream>>>(ei, E, cnt);
  k_scan<6><<<1, 1024, 0, stream>>>(cnt, n0, rowptr);
  k_fill   <<<gE, TPB, 0, stream>>>(ei, E, rowptr, fillc, colidx);
  // ---- GCN0: 3ch-aggregate then fused 3->32 GEMM + score ----
  k_agg3<<<(n0+TPB-1)/TPB, TPB, 0, stream>>>(x, cnt, rowptr, colidx, dinv0, xa, n0);
  k_gcn0<<<(n0*32+TPB-1)/TPB, TPB, 0, stream>>>(xa, W0, b0, dinv0, p0, h0, score, n0);
  // ---- pool1 (select-only) + full-grid gather-GEMM ----
  k_pool<6144><<<1, 1024, 0, stream>>>(score, n0, K1, perm1, rank1);
  k_gather_mm<<<(K1*32+TPB-1)/TPB, TPB, 0, stream>>>(h0, score, perm1, W1, hw1, K1);
  // ---- B1 CSR + dinv1 ----
  k_build_B1<<<K1, 256, 0, stream>>>(rowptr, colidx, perm1, rank1, K1,
                                     dinv1, rowbeg1, rowend1, col1, val1, cursor);
  // ---- GCN1 sparse (dinv at gather) + score ----
  k_spmm<true,true><<<(K1*32+TPB-1)/TPB, TPB, 0, stream>>>(rowbeg1, rowend1, col1, val1,
                                                           hw1, dinv1, b1, h1, K1, p1, score);
  // ---- pool2 + gather ----
  k_pool<1216><<<1, 1024, 0, stream>>>(score, K1, K2, perm2, rank2);
  k_gather_mm<<<(K2*32+TPB-1)/TPB, TPB, 0, stream>>>(h1, score, perm2, W2, hw2, K2);
  // ---- two-hop level1 -> C2 + dinv2 ----
  k_twohop_sp<<<K2, 256, 0, stream>>>(rowbeg1, rowend1, col1, val1, perm2, rank2, C2, dinv2, K2);
  // ---- GCN2 dense + score ----
  k_dgcn<true,true><<<K2, 256, 0, stream>>>(C2, hw2, dinv2, b2, h2, K2, p2, score);
  // ---- pool3 + gather ----
  k_pool<256><<<1, 1024, 0, stream>>>(score, K2, K3, perm3, rank3);
  k_gather_mm<<<(K3*32+TPB-1)/TPB, TPB, 0, stream>>>(h2, score, perm3, W3, hw3, K3);
  // ---- two-hop level2 -> C3 + dinv3 ----
  k_twohop_d3<<<K3, 256, 0, stream>>>(C2, K2, perm3, K3, C3, dinv3);
  // ---- GCN3 dense -> h3 ----
  k_dgcn<true,false><<<K3, 256, 0, stream>>>(C3, hw3, dinv3, b3, h3, K3, nullptr, nullptr);
  // ---- up0 ----
  k_addup_mm<32,false><<<(K2*32+TPB-1)/TPB, TPB, 0, stream>>>(h2, h3, rank3, Wu0, nullptr, hw2, K2);
  k_dgcn<true,false><<<K2, 256, 0, stream>>>(C2, hw2, dinv2, bu0, hu2, K2, nullptr, nullptr);
  // ---- up1 ----
  k_addup_mm<32,false><<<(K1*32+TPB-1)/TPB, TPB, 0, stream>>>(h1, hu2, rank2, Wu1, nullptr, hw1, K1);
  k_spmm<true,false><<<(K1*32+TPB-1)/TPB, TPB, 0, stream>>>(rowbeg1, rowend1, col1, val1,
                                                            hw1, dinv1, bu1, hu1, K1, nullptr, nullptr);
  // ---- up2 (32->4, dinv0 folded) + final CSR GCN + BN ----
  k_addup_mm<4,true><<<(n0*4+TPB-1)/TPB, TPB, 0, stream>>>(h0, hu1, rank1, Wu2, dinv0, hw4, n0);
  k_gcn_final<<<gBN, TPB, 0, stream>>>(rowptr, colidx, hw4, dinv0, bu2, out, n0, bnp, bnq);
  k_bn_finish<<<24, TPB, 0, stream>>>(out, n0, gBN, bnp, bnq, bng, bnb);
}